// Round 12
// baseline (323.724 us; speedup 1.0000x reference)
//
#include <hip/hip_runtime.h>

#define NN 50000
#define EE 800000
#define DIN 256
#define H 128
#define MM 64
#define CC 4
#define BB 128
#define NHEAD 8
#define HDIM 16

#define NRW 50          // node ranges (1000 nodes each)
#define RNODES 1000
#define NSB 625         // edge-slice blocks
#define ESL 1280        // edges per slice block (NSB*ESL == EE)

typedef _Float16 f16x8 __attribute__((ext_vector_type(8)));
typedef _Float16 f16x4 __attribute__((ext_vector_type(4)));
typedef float f32x4 __attribute__((ext_vector_type(4)));

// ---------------- CSR build: two-level counting sort ----------------

__launch_bounds__(256)
__global__ void ecount(const int* __restrict__ col, int* __restrict__ bcnt) {
    __shared__ int hist[NRW];
    int b = blockIdx.x, t = threadIdx.x;
    if (t < NRW) hist[t] = 0;
    __syncthreads();
    int e0 = b * ESL;
    #pragma unroll
    for (int i = 0; i < ESL / 256; i++) {
        int c = col[e0 + t + i * 256];
        atomicAdd(&hist[c / RNODES], 1);
    }
    __syncthreads();
    if (t < NRW) bcnt[t * NSB + b] = hist[t];
}

__global__ void escan(const int* __restrict__ bcnt, int* __restrict__ sbase,
                      int* __restrict__ rbase) {
    __shared__ int rt[NRW];
    int t = threadIdx.x;
    if (t < NRW) {
        int s = 0;
        for (int b = 0; b < NSB; b++) s += bcnt[t * NSB + b];
        rt[t] = s;
    }
    __syncthreads();
    if (t == 0) {
        int run = 0;
        for (int r = 0; r < NRW; r++) { rbase[r] = run; run += rt[r]; }
    }
    __syncthreads();
    if (t < NRW) {
        int run = rbase[t];
        for (int b = 0; b < NSB; b++) { sbase[t * NSB + b] = run; run += bcnt[t * NSB + b]; }
    }
}

__launch_bounds__(256)
__global__ void escatter(const int* __restrict__ row, const int* __restrict__ col,
                         const int* __restrict__ sbase, int2* __restrict__ ebuf) {
    __shared__ int cur[NRW];
    int b = blockIdx.x, t = threadIdx.x;
    if (t < NRW) cur[t] = sbase[t * NSB + b];
    __syncthreads();
    int e0 = b * ESL;
    #pragma unroll
    for (int i = 0; i < ESL / 256; i++) {
        int e = e0 + t + i * 256;
        int c = col[e];
        int u = row[e];
        int r = c / RNODES;
        int p = atomicAdd(&cur[r], 1);
        ebuf[p] = make_int2(u, c - r * RNODES);
    }
}

__launch_bounds__(512)
__global__ void csr_build(const int2* __restrict__ ebuf, const int* __restrict__ rbase,
                          int* __restrict__ degcnt, int* __restrict__ offs,
                          float* __restrict__ dis, int* __restrict__ csr) {
    __shared__ int hist[RNODES];
    __shared__ int cur[RNODES];
    __shared__ int sb[512];
    int r = blockIdx.x, t = threadIdx.x;
    int r0 = r * RNODES;
    int rb = rbase[r];
    int re = (r + 1 < NRW) ? rbase[r + 1] : EE;
    for (int i = t; i < RNODES; i += 512) hist[i] = 0;
    __syncthreads();
    for (int e = rb + t; e < re; e += 512) atomicAdd(&hist[ebuf[e].y], 1);
    __syncthreads();
    int i0 = 2 * t, i1 = 2 * t + 1;
    int d0 = (i0 < RNODES) ? hist[i0] : 0;
    int d1 = (i1 < RNODES) ? hist[i1] : 0;
    int ps = d0 + d1;
    sb[t] = ps;
    __syncthreads();
    for (int off = 1; off < 512; off <<= 1) {
        int x = (t >= off) ? sb[t - off] : 0;
        __syncthreads();
        sb[t] += x;
        __syncthreads();
    }
    int excl = sb[t] - ps;
    if (i0 < RNODES) {
        cur[i0] = excl;
        degcnt[r0 + i0] = d0;
        offs[r0 + i0] = rb + excl;
        dis[r0 + i0] = rsqrtf((float)(d0 + 1));
    }
    if (i1 < RNODES) {
        cur[i1] = excl + d0;
        degcnt[r0 + i1] = d1;
        offs[r0 + i1] = rb + excl + d0;
        dis[r0 + i1] = rsqrtf((float)(d1 + 1));
    }
    __syncthreads();
    for (int e = rb + t; e < re; e += 512) {
        int2 ed = ebuf[e];
        int p = atomicAdd(&cur[ed.y], 1);
        csr[rb + p] = ed.x;
    }
}

// ---------------- graph boundaries (batch is sorted) ----------------

__global__ void graph_bounds(const int* __restrict__ batch, int* __restrict__ gstart) {
    int v = blockIdx.x * blockDim.x + threadIdx.x;
    if (v >= NN) return;
    int b = batch[v];
    if (v == 0) {
        for (int g = 0; g <= b; g++) gstart[g] = 0;
    } else {
        int pb = batch[v - 1];
        for (int g = pb + 1; g <= b; g++) gstart[g] = v;
    }
    if (v == NN - 1) {
        for (int g = b + 1; g <= BB; g++) gstart[g] = NN;
    }
}

// ---------------- W split to frag-ordered fp16 hi/lo (one launch, all 4 weights) -------
// frag f = kt*8+ct; hi at ((f*64+l)*8+j), lo at offset KT*8*64*8 halfwords.
// Frag element (l,j) = W[kt*32+(l>>4)*8+j][ct*16+(l&15)].

__global__ void wsplit_all(const float* __restrict__ w1, const float* __restrict__ gw1,
                           const float* __restrict__ gw2, const float* __restrict__ gw3,
                           _Float16* __restrict__ wf1, _Float16* __restrict__ wfg1,
                           _Float16* __restrict__ wfg2, _Float16* __restrict__ wfg3) {
    int b = blockIdx.x;
    int l = threadIdx.x;          // 0..63
    const float* Wg; _Float16* outw; int KT, f;
    if (b < 64)       { Wg = w1;  outw = wf1;  KT = 8; f = b; }
    else if (b < 96)  { Wg = gw1; outw = wfg1; KT = 4; f = b - 64; }
    else if (b < 128) { Wg = gw2; outw = wfg2; KT = 4; f = b - 96; }
    else              { Wg = gw3; outw = wfg3; KT = 4; f = b - 128; }
    int kt = f >> 3, ct = f & 7;
    int k0 = kt * 32 + (l >> 4) * 8;
    int c = ct * 16 + (l & 15);
    f16x8 hi, lo;
    #pragma unroll
    for (int j = 0; j < 8; j++) {
        float w = Wg[(size_t)(k0 + j) * H + c];
        _Float16 hh = (_Float16)w;
        hi[j] = hh;
        lo[j] = (_Float16)(w - (float)hh);
    }
    *reinterpret_cast<f16x8*>(outw + ((size_t)f * 64 + l) * 8) = hi;
    *reinterpret_cast<f16x8*>(outw + ((size_t)KT * 8 * 64 * 8) + ((size_t)f * 64 + l) * 8) = lo;
}

// ---------------- Linear via fp16-split MFMA v3: 8 waves/block ----------------
// 512 thr = 8 waves; wave w: rows (w&3)*16..+16, cols (w>>2)*64..+64 (4 col-tiles).
// Grid = NN/64 blocks -> ~6 waves/SIMD (was 3). OMODE 0: fp32 out; OMODE 1: fp16
// out scaled by dis[r]. LN uses a cross-wave LDS reduction (two col-halves).

template <int K, bool LN, int OMODE>
__launch_bounds__(512)
__global__ void mfma_linear(const float* __restrict__ A, const _Float16* __restrict__ Wf,
                            const float* __restrict__ bias,
                            const float* __restrict__ ln_g, const float* __restrict__ ln_b,
                            const float* __restrict__ dis,
                            void* __restrict__ outp) {
    constexpr int KT = K / 32;
    __shared__ float ldsS[2][64], ldsQ[2][64];
    int t = threadIdx.x;
    int w = t >> 6, l = t & 63;
    int rg = w & 3, ch = w >> 2;
    int lm = l & 15, lg = l >> 4;
    int rowBase = blockIdx.x * 64;
    int arow = rowBase + rg * 16 + lm;
    int arc = min(arow, NN - 1);
    const f16x8* __restrict__ Bh = reinterpret_cast<const f16x8*>(Wf);
    const f16x8* __restrict__ Bl = Bh + KT * 8 * 64;

    f32x4 acc[4];
    #pragma unroll
    for (int ct = 0; ct < 4; ct++) acc[ct] = (f32x4){0.f, 0.f, 0.f, 0.f};

    #pragma unroll
    for (int kt = 0; kt < KT; kt++) {
        const float* ap = A + (size_t)arc * K + kt * 32 + lg * 8;
        float4 a0 = *(const float4*)ap;
        float4 a1 = *(const float4*)(ap + 4);
        float av[8] = {a0.x, a0.y, a0.z, a0.w, a1.x, a1.y, a1.z, a1.w};
        f16x8 ah, al;
        #pragma unroll
        for (int j = 0; j < 8; j++) {
            _Float16 hh = (_Float16)av[j];
            ah[j] = hh;
            al[j] = (_Float16)(av[j] - (float)hh);
        }
        #pragma unroll
        for (int ct = 0; ct < 4; ct++) {
            int f = kt * 8 + ch * 4 + ct;
            f16x8 bh = Bh[(size_t)f * 64 + l];
            f16x8 bl = Bl[(size_t)f * 64 + l];
            acc[ct] = __builtin_amdgcn_mfma_f32_16x16x32_f16(ah, bh, acc[ct], 0, 0, 0);
            acc[ct] = __builtin_amdgcn_mfma_f32_16x16x32_f16(ah, bl, acc[ct], 0, 0, 0);
            acc[ct] = __builtin_amdgcn_mfma_f32_16x16x32_f16(al, bh, acc[ct], 0, 0, 0);
        }
    }

    float bv[4], gv[4], lbv[4];
    #pragma unroll
    for (int ct = 0; ct < 4; ct++) {
        int c = (ch * 4 + ct) * 16 + lm;
        bv[ct] = bias[c];
        if constexpr (LN) { gv[ct] = ln_g[c]; lbv[ct] = ln_b[c]; }
    }

    float vals[4][4];
    #pragma unroll
    for (int q = 0; q < 4; q++) {
        float s = 0.f, sq = 0.f;
        #pragma unroll
        for (int ct = 0; ct < 4; ct++) {
            float v = fmaxf(acc[ct][q] + bv[ct], 0.f);
            vals[q][ct] = v;
            s += v; sq += v * v;
        }
        if constexpr (LN) {
            #pragma unroll
            for (int m = 1; m < 16; m <<= 1) {
                s  += __shfl_xor(s,  m, 64);
                sq += __shfl_xor(sq, m, 64);
            }
            if (lm == 0) {
                int r64 = rg * 16 + lg * 4 + q;
                ldsS[ch][r64] = s;
                ldsQ[ch][r64] = sq;
            }
        } else {
            int rr = rowBase + rg * 16 + lg * 4 + q;
            if (rr < NN) {
                if constexpr (OMODE == 1) {
                    _Float16* o16 = (_Float16*)outp;
                    float sc = dis[rr];
                    #pragma unroll
                    for (int ct = 0; ct < 4; ct++)
                        o16[(size_t)rr * H + (ch * 4 + ct) * 16 + lm] =
                            (_Float16)(vals[q][ct] * sc);
                } else {
                    float* o32 = (float*)outp;
                    #pragma unroll
                    for (int ct = 0; ct < 4; ct++)
                        o32[(size_t)rr * H + (ch * 4 + ct) * 16 + lm] = vals[q][ct];
                }
            }
        }
    }

    if constexpr (LN) {
        __syncthreads();
        #pragma unroll
        for (int q = 0; q < 4; q++) {
            int r64 = rg * 16 + lg * 4 + q;
            float s  = ldsS[0][r64] + ldsS[1][r64];
            float sq = ldsQ[0][r64] + ldsQ[1][r64];
            float mean = s * (1.f / 128.f);
            float var  = sq * (1.f / 128.f) - mean * mean;
            float inv  = rsqrtf(var + 1e-5f);
            int rr = rowBase + r64;
            if (rr < NN) {
                if constexpr (OMODE == 1) {
                    _Float16* o16 = (_Float16*)outp;
                    float sc = dis[rr];
                    #pragma unroll
                    for (int ct = 0; ct < 4; ct++)
                        o16[(size_t)rr * H + (ch * 4 + ct) * 16 + lm] =
                            (_Float16)(((vals[q][ct] - mean) * inv * gv[ct] + lbv[ct]) * sc);
                } else {
                    float* o32 = (float*)outp;
                    #pragma unroll
                    for (int ct = 0; ct < 4; ct++)
                        o32[(size_t)rr * H + (ch * 4 + ct) * 16 + lm] =
                            (vals[q][ct] - mean) * inv * gv[ct] + lbv[ct];
                }
            }
        }
    }
}

// ---------------- GCN aggregation: fp16 gather, fp32 accumulate ----------------

__launch_bounds__(256)
__global__ void agg_kernel(const _Float16* __restrict__ g16, const int* __restrict__ offs,
                           const int* __restrict__ degcnt, const int* __restrict__ csr,
                           const float* __restrict__ dis, float* __restrict__ out) {
    __shared__ int idx[8][64];
    int grp = threadIdx.x >> 5;        // 0..7
    int l = threadIdx.x & 31;
    int v = blockIdx.x * 8 + grp;      // grid exact: NN/8 blocks
    int beg = offs[v], cnt = degcnt[v];
    idx[grp][l]      = (l      < cnt) ? csr[beg + l]      : v;
    idx[grp][l + 32] = (l + 32 < cnt) ? csr[beg + l + 32] : v;

    const f16x4* __restrict__ G = reinterpret_cast<const f16x4*>(g16);  // 32 f16x4/row
    float dv = dis[v];
    f16x4 gvh = G[(size_t)v * 32 + l];
    float4 gv = make_float4((float)gvh[0], (float)gvh[1], (float)gvh[2], (float)gvh[3]);
    float4 acc = gv;                       // self term
    int n0 = min(cnt, 64);
    int m0 = (n0 + 7) & ~7;                // padded trip count

    for (int i = 0; i < m0; i += 8) {
        f16x4 tv[8];
        #pragma unroll
        for (int jj = 0; jj < 8; jj++)
            tv[jj] = G[(size_t)idx[grp][i + jj] * 32 + l];
        #pragma unroll
        for (int jj = 0; jj < 8; jj++) {
            acc.x += (float)tv[jj][0];
            acc.y += (float)tv[jj][1];
            acc.z += (float)tv[jj][2];
            acc.w += (float)tv[jj][3];
        }
    }
    float pad = (float)(m0 - n0);          // remove padded copies of g16[v]
    acc.x -= pad * gv.x; acc.y -= pad * gv.y;
    acc.z -= pad * gv.z; acc.w -= pad * gv.w;

    for (int i = 64; i < cnt; i++) {       // degree > 64 tail (essentially never)
        f16x4 a = G[(size_t)csr[beg + i] * 32 + l];
        acc.x += (float)a[0]; acc.y += (float)a[1];
        acc.z += (float)a[2]; acc.w += (float)a[3];
    }
    float4 o;
    o.x = dv * acc.x; o.y = dv * acc.y; o.z = dv * acc.z; o.w = dv * acc.w;
    reinterpret_cast<float4*>(out)[(size_t)v * 32 + l] = o;
}

// ---------------- mean pool: chunked segmented sum (batch sorted) ----------------

#define PCHUNK 128

__launch_bounds__(128)
__global__ void pool2_kernel(const float* __restrict__ h, const int* __restrict__ batch,
                             float* __restrict__ psums) {
    __shared__ int bl[PCHUNK];
    int t = threadIdx.x;
    int v0 = blockIdx.x * PCHUNK;
    int v1 = min(v0 + PCHUNK, NN);
    if (v0 >= NN) return;
    if (v0 + t < NN) bl[t] = batch[v0 + t];
    __syncthreads();
    int curb = bl[0];
    float acc = 0.f;
    for (int v = v0; v < v1; v++) {
        int b = bl[v - v0];                 // uniform across block
        if (b != curb) {
            atomicAdd(&psums[curb * H + t], acc);
            acc = 0.f; curb = b;
        }
        acc += h[(size_t)v * H + t];
    }
    atomicAdd(&psums[curb * H + t], acc);
}

// ---------------- memory K/V projection ----------------

__global__ void kv_kernel(const float* __restrict__ mb, const float* __restrict__ ipw,
                          const float* __restrict__ ipb,
                          float* __restrict__ kbuf, float* __restrict__ vbuf) {
    __shared__ float rowv[H];
    int m = blockIdx.x, i = threadIdx.x;
    rowv[i] = mb[m * H + i];
    __syncthreads();
    float ak = 0.f, av = 0.f;
    for (int j = 0; j < H; j++) {
        float x = rowv[j];
        ak = fmaf(x, ipw[(size_t)(H + i) * H + j], ak);
        av = fmaf(x, ipw[(size_t)(2 * H + i) * H + j], av);
    }
    kbuf[m * H + i] = ak + ipb[H + i];
    vbuf[m * H + i] = av + ipb[2 * H + i];
}

// ---------------- attention + classifier (one block per graph) ----------------

__launch_bounds__(128)
__global__ void attn_kernel(const float* __restrict__ psums, const int* __restrict__ gstart,
                            const float* __restrict__ kbuf, const float* __restrict__ vbuf,
                            const float* __restrict__ ipw, const float* __restrict__ ipb,
                            const float* __restrict__ out_w, const float* __restrict__ out_b,
                            const float* __restrict__ cw1, const float* __restrict__ cb1,
                            const float* __restrict__ cw2, const float* __restrict__ cb2,
                            float* __restrict__ out) {
    __shared__ float pooled[H], q[H], attn[H], z[2 * H], c1[H], sc[NHEAD * MM];
    int b = blockIdx.x, t = threadIdx.x;
    float cn = (float)max(gstart[b + 1] - gstart[b], 1);
    float pv = psums[b * H + t] / cn;
    pooled[t] = pv;
    z[t] = pv;
    __syncthreads();
    float a = 0.f;
    for (int j = 0; j < H; j++) a = fmaf(pooled[j], ipw[(size_t)t * H + j], a);
    q[t] = a + ipb[t];
    __syncthreads();
    for (int sidx = t; sidx < NHEAD * MM; sidx += 128) {
        int hh = sidx >> 6, m = sidx & 63;
        float s2 = 0.f;
        for (int d = 0; d < HDIM; d++)
            s2 = fmaf(q[hh * HDIM + d], kbuf[m * H + hh * HDIM + d], s2);
        sc[sidx] = s2 * 0.25f;   // 1/sqrt(16)
    }
    __syncthreads();
    if (t < NHEAD) {
        float mx = -1e30f;
        for (int m = 0; m < MM; m++) mx = fmaxf(mx, sc[t * MM + m]);
        float ssum = 0.f;
        for (int m = 0; m < MM; m++) { float e = expf(sc[t * MM + m] - mx); sc[t * MM + m] = e; ssum += e; }
        float inv = 1.f / ssum;
        for (int m = 0; m < MM; m++) sc[t * MM + m] *= inv;
    }
    __syncthreads();
    {
        int hh = t >> 4;
        float a2 = 0.f;
        for (int m = 0; m < MM; m++) a2 = fmaf(sc[hh * MM + m], vbuf[m * H + t], a2);
        attn[t] = a2;
    }
    __syncthreads();
    float mm = 0.f;
    for (int j = 0; j < H; j++) mm = fmaf(attn[j], out_w[(size_t)t * H + j], mm);
    z[H + t] = mm + out_b[t];
    __syncthreads();
    float cc = 0.f;
    for (int j = 0; j < 2 * H; j++) cc = fmaf(z[j], cw1[(size_t)j * H + t], cc);
    c1[t] = fmaxf(cc + cb1[t], 0.f);
    __syncthreads();
    if (t < CC) {
        float o = 0.f;
        for (int j = 0; j < H; j++) o = fmaf(c1[j], cw2[j * CC + t], o);
        out[b * CC + t] = o + cb2[t];
    }
}

// ---------------- launch ----------------

extern "C" void kernel_launch(void* const* d_in, const int* in_sizes, int n_in,
                              void* d_out, int out_size, void* d_ws, size_t ws_size,
                              hipStream_t stream) {
    const float* x      = (const float*)d_in[0];
    const int*   eidx   = (const int*)d_in[1];
    const int*   batch  = (const int*)d_in[2];
    const float* w1     = (const float*)d_in[3];
    const float* b1     = (const float*)d_in[4];
    const float* ln_g   = (const float*)d_in[5];
    const float* ln_b   = (const float*)d_in[6];
    const float* gw1    = (const float*)d_in[7];
    const float* gb1    = (const float*)d_in[8];
    const float* gw2    = (const float*)d_in[9];
    const float* gb2    = (const float*)d_in[10];
    const float* gw3    = (const float*)d_in[11];
    const float* gb3    = (const float*)d_in[12];
    const float* memb   = (const float*)d_in[13];
    const float* ipw    = (const float*)d_in[14];
    const float* ipb    = (const float*)d_in[15];
    const float* out_w  = (const float*)d_in[16];
    const float* out_b  = (const float*)d_in[17];
    const float* cw1    = (const float*)d_in[18];
    const float* cb1    = (const float*)d_in[19];
    const float* cw2    = (const float*)d_in[20];
    const float* cb2    = (const float*)d_in[21];

    const int* row = eidx;
    const int* col = eidx + EE;

    char* ws = (char*)d_ws;
    size_t off = 0;
    auto alloc = [&](size_t bytes) -> void* {
        void* p = ws + off;
        off += (bytes + 255) & ~(size_t)255;
        return p;
    };
    float* h_cur  = (float*)alloc((size_t)NN * H * 4);
    float* h_tmp  = (float*)alloc((size_t)NN * H * 4);
    _Float16* g16 = (_Float16*)alloc((size_t)NN * H * 2);
    char*  zbeg   = ws + off;
    float* psums  = (float*)alloc((size_t)BB * H * 4);
    size_t zbytes = (size_t)((ws + off) - zbeg);
    int*   degcnt = (int*)alloc((size_t)NN * 4);
    float* dis    = (float*)alloc((size_t)NN * 4);
    int*   offs   = (int*)alloc((size_t)NN * 4);
    int*   csr    = (int*)alloc((size_t)EE * 4);
    int2*  ebuf   = (int2*)alloc((size_t)EE * 8);
    int*   bcnt   = (int*)alloc((size_t)NRW * NSB * 4);
    int*   sbase  = (int*)alloc((size_t)NRW * NSB * 4);
    int*   rbase  = (int*)alloc(256);
    int*   gstart = (int*)alloc((size_t)(BB + 1) * 4);
    float* kbuf   = (float*)alloc((size_t)MM * H * 4);
    float* vbuf   = (float*)alloc((size_t)MM * H * 4);
    _Float16* wf1 = (_Float16*)alloc((size_t)2 * DIN * H * 2);   // 256 KB (hi+lo)
    _Float16* wfg1 = (_Float16*)alloc((size_t)2 * H * H * 2);    // 128 KB
    _Float16* wfg2 = (_Float16*)alloc((size_t)2 * H * H * 2);
    _Float16* wfg3 = (_Float16*)alloc((size_t)2 * H * H * 2);
    (void)ws_size; (void)in_sizes; (void)n_in; (void)out_size;

    hipMemsetAsync(zbeg, 0, zbytes, stream);   // psums

    // CSR build: fully-parallel two-level counting sort
    ecount<<<NSB, 256, 0, stream>>>(col, bcnt);
    escan<<<1, 64, 0, stream>>>(bcnt, sbase, rbase);
    escatter<<<NSB, 256, 0, stream>>>(row, col, sbase, ebuf);
    csr_build<<<NRW, 512, 0, stream>>>(ebuf, rbase, degcnt, offs, dis, csr);

    graph_bounds<<<(NN + 255) / 256, 256, 0, stream>>>(batch, gstart);

    // W-split precompute: one launch for all 4 weights (64 + 3*32 = 160 frag-blocks)
    wsplit_all<<<160, 64, 0, stream>>>(w1, gw1, gw2, gw3, wf1, wfg1, wfg2, wfg3);

    const int LGRID = (NN + 63) / 64;   // 782 (512-thread blocks)
    const int AGRID = NN / 8;           // 6250 (exact)

    // feature transform -> g1 (fp16, dis-scaled)
    mfma_linear<DIN, true, 1><<<LGRID, 512, 0, stream>>>(x, wf1, b1, ln_g, ln_b, dis, g16);

    // GCN layer 1
    agg_kernel<<<AGRID, 256, 0, stream>>>(g16, offs, degcnt, csr, dis, h_tmp);
    mfma_linear<H, false, 1><<<LGRID, 512, 0, stream>>>(h_tmp, wfg1, gb1, nullptr, nullptr, dis, g16);
    // GCN layer 2
    agg_kernel<<<AGRID, 256, 0, stream>>>(g16, offs, degcnt, csr, dis, h_tmp);
    mfma_linear<H, false, 1><<<LGRID, 512, 0, stream>>>(h_tmp, wfg2, gb2, nullptr, nullptr, dis, g16);
    // GCN layer 3 (fp32 unscaled output -> pool)
    agg_kernel<<<AGRID, 256, 0, stream>>>(g16, offs, degcnt, csr, dis, h_tmp);
    mfma_linear<H, false, 0><<<LGRID, 512, 0, stream>>>(h_tmp, wfg3, gb3, nullptr, nullptr, dis, h_cur);

    pool2_kernel<<<(NN + PCHUNK - 1) / PCHUNK, PCHUNK, 0, stream>>>(h_cur, batch, psums);
    kv_kernel<<<MM, H, 0, stream>>>(memb, ipw, ipb, kbuf, vbuf);
    attn_kernel<<<BB, H, 0, stream>>>(psums, gstart, kbuf, vbuf, ipw, ipb, out_w, out_b,
                                      cw1, cb1, cw2, cb2, (float*)d_out);
}

// Round 13
// 274.980 us; speedup vs baseline: 1.1773x; 1.1773x over previous
//
#include <hip/hip_runtime.h>

#define NN 50000
#define EE 800000
#define DIN 256
#define H 128
#define MM 64
#define CC 4
#define BB 128
#define NHEAD 8
#define HDIM 16

#define NRW 50          // node ranges (1000 nodes each)
#define RNODES 1000
#define NSB 625         // edge-slice blocks
#define ESL 1280        // edges per slice block (NSB*ESL == EE)

typedef _Float16 f16x8 __attribute__((ext_vector_type(8)));
typedef _Float16 f16x4 __attribute__((ext_vector_type(4)));
typedef float f32x4 __attribute__((ext_vector_type(4)));

// ---------------- CSR build: two-level counting sort ----------------

__launch_bounds__(256)
__global__ void ecount(const int* __restrict__ col, int* __restrict__ bcnt) {
    __shared__ int hist[NRW];
    int b = blockIdx.x, t = threadIdx.x;
    if (t < NRW) hist[t] = 0;
    __syncthreads();
    int e0 = b * ESL;
    #pragma unroll
    for (int i = 0; i < ESL / 256; i++) {
        int c = col[e0 + t + i * 256];
        atomicAdd(&hist[c / RNODES], 1);
    }
    __syncthreads();
    if (t < NRW) bcnt[t * NSB + b] = hist[t];
}

__global__ void escan(const int* __restrict__ bcnt, int* __restrict__ sbase,
                      int* __restrict__ rbase) {
    __shared__ int rt[NRW];
    int t = threadIdx.x;
    if (t < NRW) {
        int s = 0;
        for (int b = 0; b < NSB; b++) s += bcnt[t * NSB + b];
        rt[t] = s;
    }
    __syncthreads();
    if (t == 0) {
        int run = 0;
        for (int r = 0; r < NRW; r++) { rbase[r] = run; run += rt[r]; }
    }
    __syncthreads();
    if (t < NRW) {
        int run = rbase[t];
        for (int b = 0; b < NSB; b++) { sbase[t * NSB + b] = run; run += bcnt[t * NSB + b]; }
    }
}

__launch_bounds__(256)
__global__ void escatter(const int* __restrict__ row, const int* __restrict__ col,
                         const int* __restrict__ sbase, int2* __restrict__ ebuf) {
    __shared__ int cur[NRW];
    int b = blockIdx.x, t = threadIdx.x;
    if (t < NRW) cur[t] = sbase[t * NSB + b];
    __syncthreads();
    int e0 = b * ESL;
    #pragma unroll
    for (int i = 0; i < ESL / 256; i++) {
        int e = e0 + t + i * 256;
        int c = col[e];
        int u = row[e];
        int r = c / RNODES;
        int p = atomicAdd(&cur[r], 1);
        ebuf[p] = make_int2(u, c - r * RNODES);
    }
}

__launch_bounds__(512)
__global__ void csr_build(const int2* __restrict__ ebuf, const int* __restrict__ rbase,
                          int* __restrict__ degcnt, int* __restrict__ offs,
                          float* __restrict__ dis, int* __restrict__ csr) {
    __shared__ int hist[RNODES];
    __shared__ int cur[RNODES];
    __shared__ int sb[512];
    int r = blockIdx.x, t = threadIdx.x;
    int r0 = r * RNODES;
    int rb = rbase[r];
    int re = (r + 1 < NRW) ? rbase[r + 1] : EE;
    for (int i = t; i < RNODES; i += 512) hist[i] = 0;
    __syncthreads();
    for (int e = rb + t; e < re; e += 512) atomicAdd(&hist[ebuf[e].y], 1);
    __syncthreads();
    int i0 = 2 * t, i1 = 2 * t + 1;
    int d0 = (i0 < RNODES) ? hist[i0] : 0;
    int d1 = (i1 < RNODES) ? hist[i1] : 0;
    int ps = d0 + d1;
    sb[t] = ps;
    __syncthreads();
    for (int off = 1; off < 512; off <<= 1) {
        int x = (t >= off) ? sb[t - off] : 0;
        __syncthreads();
        sb[t] += x;
        __syncthreads();
    }
    int excl = sb[t] - ps;
    if (i0 < RNODES) {
        cur[i0] = excl;
        degcnt[r0 + i0] = d0;
        offs[r0 + i0] = rb + excl;
        dis[r0 + i0] = rsqrtf((float)(d0 + 1));
    }
    if (i1 < RNODES) {
        cur[i1] = excl + d0;
        degcnt[r0 + i1] = d1;
        offs[r0 + i1] = rb + excl + d0;
        dis[r0 + i1] = rsqrtf((float)(d1 + 1));
    }
    __syncthreads();
    for (int e = rb + t; e < re; e += 512) {
        int2 ed = ebuf[e];
        int p = atomicAdd(&cur[ed.y], 1);
        csr[rb + p] = ed.x;
    }
}

// ---------------- graph boundaries (batch is sorted) ----------------

__global__ void graph_bounds(const int* __restrict__ batch, int* __restrict__ gstart) {
    int v = blockIdx.x * blockDim.x + threadIdx.x;
    if (v >= NN) return;
    int b = batch[v];
    if (v == 0) {
        for (int g = 0; g <= b; g++) gstart[g] = 0;
    } else {
        int pb = batch[v - 1];
        for (int g = pb + 1; g <= b; g++) gstart[g] = v;
    }
    if (v == NN - 1) {
        for (int g = b + 1; g <= BB; g++) gstart[g] = NN;
    }
}

// ---------------- W split to frag-ordered fp16 hi/lo (one launch, all 4 weights) -------

__global__ void wsplit_all(const float* __restrict__ w1, const float* __restrict__ gw1,
                           const float* __restrict__ gw2, const float* __restrict__ gw3,
                           _Float16* __restrict__ wf1, _Float16* __restrict__ wfg1,
                           _Float16* __restrict__ wfg2, _Float16* __restrict__ wfg3) {
    int b = blockIdx.x;
    int l = threadIdx.x;          // 0..63
    const float* Wg; _Float16* outw; int KT, f;
    if (b < 64)       { Wg = w1;  outw = wf1;  KT = 8; f = b; }
    else if (b < 96)  { Wg = gw1; outw = wfg1; KT = 4; f = b - 64; }
    else if (b < 128) { Wg = gw2; outw = wfg2; KT = 4; f = b - 96; }
    else              { Wg = gw3; outw = wfg3; KT = 4; f = b - 128; }
    int kt = f >> 3, ct = f & 7;
    int k0 = kt * 32 + (l >> 4) * 8;
    int c = ct * 16 + (l & 15);
    f16x8 hi, lo;
    #pragma unroll
    for (int j = 0; j < 8; j++) {
        float w = Wg[(size_t)(k0 + j) * H + c];
        _Float16 hh = (_Float16)w;
        hi[j] = hh;
        lo[j] = (_Float16)(w - (float)hh);
    }
    *reinterpret_cast<f16x8*>(outw + ((size_t)f * 64 + l) * 8) = hi;
    *reinterpret_cast<f16x8*>(outw + ((size_t)KT * 8 * 64 * 8) + ((size_t)f * 64 + l) * 8) = lo;
}

// ---------------- Linear via fp16-split MFMA (4 waves, R11 structure) ----------------
// OMODE 0: fp32 out.  OMODE 1: fp16 out scaled by dis[r].
// POOL: skip global store; segmented mean-pool partial sums (batch sorted) into
// psums via LDS tile + 1 atomic per column per run.

template <int K, bool LN, int OMODE, bool POOL>
__launch_bounds__(256)
__global__ void mfma_linear(const float* __restrict__ A, const _Float16* __restrict__ Wf,
                            const float* __restrict__ bias,
                            const float* __restrict__ ln_g, const float* __restrict__ ln_b,
                            const float* __restrict__ dis, const int* __restrict__ batch,
                            void* __restrict__ outp) {
    constexpr int KT = K / 32;
    int t = threadIdx.x;
    int wv = t >> 6, l = t & 63;
    int lm = l & 15, lg = l >> 4;
    int rowBase = blockIdx.x * 64;
    int arow = rowBase + wv * 16 + lm;
    int arc = min(arow, NN - 1);
    const f16x8* __restrict__ Bh = reinterpret_cast<const f16x8*>(Wf);
    const f16x8* __restrict__ Bl = Bh + KT * 8 * 64;

    f32x4 acc[8];
    #pragma unroll
    for (int ct = 0; ct < 8; ct++) acc[ct] = (f32x4){0.f, 0.f, 0.f, 0.f};

    #pragma unroll
    for (int kt = 0; kt < KT; kt++) {
        const float* ap = A + (size_t)arc * K + kt * 32 + lg * 8;
        float4 a0 = *(const float4*)ap;
        float4 a1 = *(const float4*)(ap + 4);
        float av[8] = {a0.x, a0.y, a0.z, a0.w, a1.x, a1.y, a1.z, a1.w};
        f16x8 ah, al;
        #pragma unroll
        for (int j = 0; j < 8; j++) {
            _Float16 hh = (_Float16)av[j];
            ah[j] = hh;
            al[j] = (_Float16)(av[j] - (float)hh);
        }
        #pragma unroll
        for (int ct = 0; ct < 8; ct++) {
            f16x8 bh = Bh[(size_t)(kt * 8 + ct) * 64 + l];
            f16x8 bl = Bl[(size_t)(kt * 8 + ct) * 64 + l];
            acc[ct] = __builtin_amdgcn_mfma_f32_16x16x32_f16(ah, bh, acc[ct], 0, 0, 0);
            acc[ct] = __builtin_amdgcn_mfma_f32_16x16x32_f16(ah, bl, acc[ct], 0, 0, 0);
            acc[ct] = __builtin_amdgcn_mfma_f32_16x16x32_f16(al, bh, acc[ct], 0, 0, 0);
        }
    }

    float bv[8], gv[8], lbv[8];
    #pragma unroll
    for (int ct = 0; ct < 8; ct++) {
        int c = ct * 16 + lm;
        bv[ct] = bias[c];
        if constexpr (LN) { gv[ct] = ln_g[c]; lbv[ct] = ln_b[c]; }
    }

    float vals[4][8];
    #pragma unroll
    for (int q = 0; q < 4; q++) {
        float s = 0.f, sq = 0.f;
        #pragma unroll
        for (int ct = 0; ct < 8; ct++) {
            float v = fmaxf(acc[ct][q] + bv[ct], 0.f);
            vals[q][ct] = v;
            s += v; sq += v * v;
        }
        if constexpr (LN) {
            #pragma unroll
            for (int m = 1; m < 16; m <<= 1) {
                s  += __shfl_xor(s,  m, 64);
                sq += __shfl_xor(sq, m, 64);
            }
            float mean = s * (1.f / 128.f);
            float var  = sq * (1.f / 128.f) - mean * mean;
            float inv  = rsqrtf(var + 1e-5f);
            #pragma unroll
            for (int ct = 0; ct < 8; ct++)
                vals[q][ct] = (vals[q][ct] - mean) * inv * gv[ct] + lbv[ct];
        }
    }

    if constexpr (POOL) {
        // stage tile in LDS (row pad +1 breaks write conflicts), then per-column
        // run-accumulate over sorted batch -> ~1 atomic per column per block.
        __shared__ float tile[64][129];
        __shared__ int bl64[64];
        float* psums = (float*)outp;
        #pragma unroll
        for (int q = 0; q < 4; q++) {
            int r64 = wv * 16 + lg * 4 + q;
            #pragma unroll
            for (int ct = 0; ct < 8; ct++)
                tile[r64][ct * 16 + lm] = vals[q][ct];
        }
        if (t < 64) bl64[t] = batch[min(rowBase + t, NN - 1)];
        __syncthreads();
        if (t < H) {
            float pacc = 0.f;
            int curb = bl64[0];
            int rmax = min(64, NN - rowBase);
            for (int r = 0; r < rmax; r++) {
                int b = bl64[r];
                if (b != curb) {
                    atomicAdd(&psums[curb * H + t], pacc);
                    pacc = 0.f; curb = b;
                }
                pacc += tile[r][t];
            }
            atomicAdd(&psums[curb * H + t], pacc);
        }
    } else {
        #pragma unroll
        for (int q = 0; q < 4; q++) {
            int rr = rowBase + wv * 16 + lg * 4 + q;
            if (rr < NN) {
                if constexpr (OMODE == 1) {
                    _Float16* o16 = (_Float16*)outp;
                    float sc = dis[rr];
                    #pragma unroll
                    for (int ct = 0; ct < 8; ct++)
                        o16[(size_t)rr * H + ct * 16 + lm] = (_Float16)(vals[q][ct] * sc);
                } else {
                    float* o32 = (float*)outp;
                    #pragma unroll
                    for (int ct = 0; ct < 8; ct++)
                        o32[(size_t)rr * H + ct * 16 + lm] = vals[q][ct];
                }
            }
        }
    }
}

// ---------------- GCN aggregation: fp16 gather, fp32 accumulate ----------------

__launch_bounds__(256)
__global__ void agg_kernel(const _Float16* __restrict__ g16, const int* __restrict__ offs,
                           const int* __restrict__ degcnt, const int* __restrict__ csr,
                           const float* __restrict__ dis, float* __restrict__ out) {
    __shared__ int idx[8][64];
    int grp = threadIdx.x >> 5;        // 0..7
    int l = threadIdx.x & 31;
    int v = blockIdx.x * 8 + grp;      // grid exact: NN/8 blocks
    int beg = offs[v], cnt = degcnt[v];
    idx[grp][l]      = (l      < cnt) ? csr[beg + l]      : v;
    idx[grp][l + 32] = (l + 32 < cnt) ? csr[beg + l + 32] : v;

    const f16x4* __restrict__ G = reinterpret_cast<const f16x4*>(g16);  // 32 f16x4/row
    float dv = dis[v];
    f16x4 gvh = G[(size_t)v * 32 + l];
    float4 gv = make_float4((float)gvh[0], (float)gvh[1], (float)gvh[2], (float)gvh[3]);
    float4 acc = gv;                       // self term
    int n0 = min(cnt, 64);
    int m0 = (n0 + 7) & ~7;                // padded trip count

    for (int i = 0; i < m0; i += 8) {
        f16x4 tv[8];
        #pragma unroll
        for (int jj = 0; jj < 8; jj++)
            tv[jj] = G[(size_t)idx[grp][i + jj] * 32 + l];
        #pragma unroll
        for (int jj = 0; jj < 8; jj++) {
            acc.x += (float)tv[jj][0];
            acc.y += (float)tv[jj][1];
            acc.z += (float)tv[jj][2];
            acc.w += (float)tv[jj][3];
        }
    }
    float pad = (float)(m0 - n0);          // remove padded copies of g16[v]
    acc.x -= pad * gv.x; acc.y -= pad * gv.y;
    acc.z -= pad * gv.z; acc.w -= pad * gv.w;

    for (int i = 64; i < cnt; i++) {       // degree > 64 tail (essentially never)
        f16x4 a = G[(size_t)csr[beg + i] * 32 + l];
        acc.x += (float)a[0]; acc.y += (float)a[1];
        acc.z += (float)a[2]; acc.w += (float)a[3];
    }
    float4 o;
    o.x = dv * acc.x; o.y = dv * acc.y; o.z = dv * acc.z; o.w = dv * acc.w;
    reinterpret_cast<float4*>(out)[(size_t)v * 32 + l] = o;
}

// ---------------- memory K/V projection ----------------

__global__ void kv_kernel(const float* __restrict__ mb, const float* __restrict__ ipw,
                          const float* __restrict__ ipb,
                          float* __restrict__ kbuf, float* __restrict__ vbuf) {
    __shared__ float rowv[H];
    int m = blockIdx.x, i = threadIdx.x;
    rowv[i] = mb[m * H + i];
    __syncthreads();
    float ak = 0.f, av = 0.f;
    for (int j = 0; j < H; j++) {
        float x = rowv[j];
        ak = fmaf(x, ipw[(size_t)(H + i) * H + j], ak);
        av = fmaf(x, ipw[(size_t)(2 * H + i) * H + j], av);
    }
    kbuf[m * H + i] = ak + ipb[H + i];
    vbuf[m * H + i] = av + ipb[2 * H + i];
}

// ---------------- attention + classifier (one block per graph) ----------------

__launch_bounds__(128)
__global__ void attn_kernel(const float* __restrict__ psums, const int* __restrict__ gstart,
                            const float* __restrict__ kbuf, const float* __restrict__ vbuf,
                            const float* __restrict__ ipw, const float* __restrict__ ipb,
                            const float* __restrict__ out_w, const float* __restrict__ out_b,
                            const float* __restrict__ cw1, const float* __restrict__ cb1,
                            const float* __restrict__ cw2, const float* __restrict__ cb2,
                            float* __restrict__ out) {
    __shared__ float pooled[H], q[H], attn[H], z[2 * H], c1[H], sc[NHEAD * MM];
    int b = blockIdx.x, t = threadIdx.x;
    float cn = (float)max(gstart[b + 1] - gstart[b], 1);
    float pv = psums[b * H + t] / cn;
    pooled[t] = pv;
    z[t] = pv;
    __syncthreads();
    float a = 0.f;
    for (int j = 0; j < H; j++) a = fmaf(pooled[j], ipw[(size_t)t * H + j], a);
    q[t] = a + ipb[t];
    __syncthreads();
    for (int sidx = t; sidx < NHEAD * MM; sidx += 128) {
        int hh = sidx >> 6, m = sidx & 63;
        float s2 = 0.f;
        for (int d = 0; d < HDIM; d++)
            s2 = fmaf(q[hh * HDIM + d], kbuf[m * H + hh * HDIM + d], s2);
        sc[sidx] = s2 * 0.25f;   // 1/sqrt(16)
    }
    __syncthreads();
    if (t < NHEAD) {
        float mx = -1e30f;
        for (int m = 0; m < MM; m++) mx = fmaxf(mx, sc[t * MM + m]);
        float ssum = 0.f;
        for (int m = 0; m < MM; m++) { float e = expf(sc[t * MM + m] - mx); sc[t * MM + m] = e; ssum += e; }
        float inv = 1.f / ssum;
        for (int m = 0; m < MM; m++) sc[t * MM + m] *= inv;
    }
    __syncthreads();
    {
        int hh = t >> 4;
        float a2 = 0.f;
        for (int m = 0; m < MM; m++) a2 = fmaf(sc[hh * MM + m], vbuf[m * H + t], a2);
        attn[t] = a2;
    }
    __syncthreads();
    float mm = 0.f;
    for (int j = 0; j < H; j++) mm = fmaf(attn[j], out_w[(size_t)t * H + j], mm);
    z[H + t] = mm + out_b[t];
    __syncthreads();
    float cc = 0.f;
    for (int j = 0; j < 2 * H; j++) cc = fmaf(z[j], cw1[(size_t)j * H + t], cc);
    c1[t] = fmaxf(cc + cb1[t], 0.f);
    __syncthreads();
    if (t < CC) {
        float o = 0.f;
        for (int j = 0; j < H; j++) o = fmaf(c1[j], cw2[j * CC + t], o);
        out[b * CC + t] = o + cb2[t];
    }
}

// ---------------- launch ----------------

extern "C" void kernel_launch(void* const* d_in, const int* in_sizes, int n_in,
                              void* d_out, int out_size, void* d_ws, size_t ws_size,
                              hipStream_t stream) {
    const float* x      = (const float*)d_in[0];
    const int*   eidx   = (const int*)d_in[1];
    const int*   batch  = (const int*)d_in[2];
    const float* w1     = (const float*)d_in[3];
    const float* b1     = (const float*)d_in[4];
    const float* ln_g   = (const float*)d_in[5];
    const float* ln_b   = (const float*)d_in[6];
    const float* gw1    = (const float*)d_in[7];
    const float* gb1    = (const float*)d_in[8];
    const float* gw2    = (const float*)d_in[9];
    const float* gb2    = (const float*)d_in[10];
    const float* gw3    = (const float*)d_in[11];
    const float* gb3    = (const float*)d_in[12];
    const float* memb   = (const float*)d_in[13];
    const float* ipw    = (const float*)d_in[14];
    const float* ipb    = (const float*)d_in[15];
    const float* out_w  = (const float*)d_in[16];
    const float* out_b  = (const float*)d_in[17];
    const float* cw1    = (const float*)d_in[18];
    const float* cb1    = (const float*)d_in[19];
    const float* cw2    = (const float*)d_in[20];
    const float* cb2    = (const float*)d_in[21];

    const int* row = eidx;
    const int* col = eidx + EE;

    char* ws = (char*)d_ws;
    size_t off = 0;
    auto alloc = [&](size_t bytes) -> void* {
        void* p = ws + off;
        off += (bytes + 255) & ~(size_t)255;
        return p;
    };
    float* h_tmp  = (float*)alloc((size_t)NN * H * 4);
    _Float16* g16 = (_Float16*)alloc((size_t)NN * H * 2);
    char*  zbeg   = ws + off;
    float* psums  = (float*)alloc((size_t)BB * H * 4);
    size_t zbytes = (size_t)((ws + off) - zbeg);
    int*   degcnt = (int*)alloc((size_t)NN * 4);
    float* dis    = (float*)alloc((size_t)NN * 4);
    int*   offs   = (int*)alloc((size_t)NN * 4);
    int*   csr    = (int*)alloc((size_t)EE * 4);
    int2*  ebuf   = (int2*)alloc((size_t)EE * 8);
    int*   bcnt   = (int*)alloc((size_t)NRW * NSB * 4);
    int*   sbase  = (int*)alloc((size_t)NRW * NSB * 4);
    int*   rbase  = (int*)alloc(256);
    int*   gstart = (int*)alloc((size_t)(BB + 1) * 4);
    float* kbuf   = (float*)alloc((size_t)MM * H * 4);
    float* vbuf   = (float*)alloc((size_t)MM * H * 4);
    _Float16* wf1 = (_Float16*)alloc((size_t)2 * DIN * H * 2);   // 256 KB (hi+lo)
    _Float16* wfg1 = (_Float16*)alloc((size_t)2 * H * H * 2);    // 128 KB
    _Float16* wfg2 = (_Float16*)alloc((size_t)2 * H * H * 2);
    _Float16* wfg3 = (_Float16*)alloc((size_t)2 * H * H * 2);
    (void)ws_size; (void)in_sizes; (void)n_in; (void)out_size;

    hipMemsetAsync(zbeg, 0, zbytes, stream);   // psums

    // CSR build: fully-parallel two-level counting sort
    ecount<<<NSB, 256, 0, stream>>>(col, bcnt);
    escan<<<1, 64, 0, stream>>>(bcnt, sbase, rbase);
    escatter<<<NSB, 256, 0, stream>>>(row, col, sbase, ebuf);
    csr_build<<<NRW, 512, 0, stream>>>(ebuf, rbase, degcnt, offs, dis, csr);

    graph_bounds<<<(NN + 255) / 256, 256, 0, stream>>>(batch, gstart);

    // W-split precompute: one launch for all 4 weights
    wsplit_all<<<160, 64, 0, stream>>>(w1, gw1, gw2, gw3, wf1, wfg1, wfg2, wfg3);

    const int LGRID = (NN + 63) / 64;   // 782
    const int AGRID = NN / 8;           // 6250 (exact)

    // feature transform -> g1 (fp16, dis-scaled)
    mfma_linear<DIN, true, 1, false><<<LGRID, 256, 0, stream>>>(x, wf1, b1, ln_g, ln_b, dis, nullptr, g16);

    // GCN layer 1
    agg_kernel<<<AGRID, 256, 0, stream>>>(g16, offs, degcnt, csr, dis, h_tmp);
    mfma_linear<H, false, 1, false><<<LGRID, 256, 0, stream>>>(h_tmp, wfg1, gb1, nullptr, nullptr, dis, nullptr, g16);
    // GCN layer 2
    agg_kernel<<<AGRID, 256, 0, stream>>>(g16, offs, degcnt, csr, dis, h_tmp);
    mfma_linear<H, false, 1, false><<<LGRID, 256, 0, stream>>>(h_tmp, wfg2, gb2, nullptr, nullptr, dis, nullptr, g16);
    // GCN layer 3: fused mean-pool epilogue (no h_cur, no pool2 kernel)
    agg_kernel<<<AGRID, 256, 0, stream>>>(g16, offs, degcnt, csr, dis, h_tmp);
    mfma_linear<H, false, 0, true><<<LGRID, 256, 0, stream>>>(h_tmp, wfg3, gb3, nullptr, nullptr, dis, batch, psums);

    kv_kernel<<<MM, H, 0, stream>>>(memb, ipw, ipb, kbuf, vbuf);
    attn_kernel<<<BB, H, 0, stream>>>(psums, gstart, kbuf, vbuf, ipw, ipb, out_w, out_b,
                                      cw1, cb1, cw2, cb2, (float*)d_out);
}

// Round 16
// 269.196 us; speedup vs baseline: 1.2026x; 1.0215x over previous
//
#include <hip/hip_runtime.h>

#define NN 50000
#define EE 800000
#define DIN 256
#define H 128
#define MM 64
#define CC 4
#define BB 128
#define NHEAD 8
#define HDIM 16

#define NRW 50          // node ranges (1000 nodes each)
#define RNODES 1000
#define NSB 625         // edge-slice blocks
#define ESL 1280        // edges per slice block (NSB*ESL == EE)

typedef _Float16 f16x8 __attribute__((ext_vector_type(8)));
typedef _Float16 f16x4 __attribute__((ext_vector_type(4)));
typedef float f32x4 __attribute__((ext_vector_type(4)));

// ---------------- CSR build: two-level counting sort ----------------

__launch_bounds__(256)
__global__ void ecount(const int* __restrict__ col, int* __restrict__ bcnt) {
    __shared__ int hist[NRW];
    int b = blockIdx.x, t = threadIdx.x;
    if (t < NRW) hist[t] = 0;
    __syncthreads();
    int e0 = b * ESL;
    #pragma unroll
    for (int i = 0; i < ESL / 256; i++) {
        int c = col[e0 + t + i * 256];
        atomicAdd(&hist[c / RNODES], 1);
    }
    __syncthreads();
    if (t < NRW) bcnt[t * NSB + b] = hist[t];
}

__global__ void escan(const int* __restrict__ bcnt, int* __restrict__ sbase,
                      int* __restrict__ rbase) {
    __shared__ int rt[NRW];
    int t = threadIdx.x;
    if (t < NRW) {
        int s = 0;
        for (int b = 0; b < NSB; b++) s += bcnt[t * NSB + b];
        rt[t] = s;
    }
    __syncthreads();
    if (t == 0) {
        int run = 0;
        for (int r = 0; r < NRW; r++) { rbase[r] = run; run += rt[r]; }
    }
    __syncthreads();
    if (t < NRW) {
        int run = rbase[t];
        for (int b = 0; b < NSB; b++) { sbase[t * NSB + b] = run; run += bcnt[t * NSB + b]; }
    }
}

__launch_bounds__(256)
__global__ void escatter(const int* __restrict__ row, const int* __restrict__ col,
                         const int* __restrict__ sbase, int2* __restrict__ ebuf) {
    __shared__ int cur[NRW];
    int b = blockIdx.x, t = threadIdx.x;
    if (t < NRW) cur[t] = sbase[t * NSB + b];
    __syncthreads();
    int e0 = b * ESL;
    #pragma unroll
    for (int i = 0; i < ESL / 256; i++) {
        int e = e0 + t + i * 256;
        int c = col[e];
        int u = row[e];
        int r = c / RNODES;
        int p = atomicAdd(&cur[r], 1);
        ebuf[p] = make_int2(u, c - r * RNODES);
    }
}

__launch_bounds__(512)
__global__ void csr_build(const int2* __restrict__ ebuf, const int* __restrict__ rbase,
                          int* __restrict__ degcnt, int* __restrict__ offs,
                          float* __restrict__ dis, int* __restrict__ csr) {
    __shared__ int hist[RNODES];
    __shared__ int cur[RNODES];
    __shared__ int sb[512];
    int r = blockIdx.x, t = threadIdx.x;
    int r0 = r * RNODES;
    int rb = rbase[r];
    int re = (r + 1 < NRW) ? rbase[r + 1] : EE;
    for (int i = t; i < RNODES; i += 512) hist[i] = 0;
    __syncthreads();
    for (int e = rb + t; e < re; e += 512) atomicAdd(&hist[ebuf[e].y], 1);
    __syncthreads();
    int i0 = 2 * t, i1 = 2 * t + 1;
    int d0 = (i0 < RNODES) ? hist[i0] : 0;
    int d1 = (i1 < RNODES) ? hist[i1] : 0;
    int ps = d0 + d1;
    sb[t] = ps;
    __syncthreads();
    for (int off = 1; off < 512; off <<= 1) {
        int x = (t >= off) ? sb[t - off] : 0;
        __syncthreads();
        sb[t] += x;
        __syncthreads();
    }
    int excl = sb[t] - ps;
    if (i0 < RNODES) {
        cur[i0] = excl;
        degcnt[r0 + i0] = d0;
        offs[r0 + i0] = rb + excl;
        dis[r0 + i0] = rsqrtf((float)(d0 + 1));
    }
    if (i1 < RNODES) {
        cur[i1] = excl + d0;
        degcnt[r0 + i1] = d1;
        offs[r0 + i1] = rb + excl + d0;
        dis[r0 + i1] = rsqrtf((float)(d1 + 1));
    }
    __syncthreads();
    for (int e = rb + t; e < re; e += 512) {
        int2 ed = ebuf[e];
        int p = atomicAdd(&cur[ed.y], 1);
        csr[rb + p] = ed.x;
    }
}

// ---------------- graph boundaries (batch is sorted) ----------------

__global__ void graph_bounds(const int* __restrict__ batch, int* __restrict__ gstart) {
    int v = blockIdx.x * blockDim.x + threadIdx.x;
    if (v >= NN) return;
    int b = batch[v];
    if (v == 0) {
        for (int g = 0; g <= b; g++) gstart[g] = 0;
    } else {
        int pb = batch[v - 1];
        for (int g = pb + 1; g <= b; g++) gstart[g] = v;
    }
    if (v == NN - 1) {
        for (int g = b + 1; g <= BB; g++) gstart[g] = NN;
    }
}

// ---------------- W split to frag-ordered fp16 hi/lo (one launch, all 4 weights) -------

__global__ void wsplit_all(const float* __restrict__ w1, const float* __restrict__ gw1,
                           const float* __restrict__ gw2, const float* __restrict__ gw3,
                           _Float16* __restrict__ wf1, _Float16* __restrict__ wfg1,
                           _Float16* __restrict__ wfg2, _Float16* __restrict__ wfg3) {
    int b = blockIdx.x;
    int l = threadIdx.x;          // 0..63
    const float* Wg; _Float16* outw; int KT, f;
    if (b < 64)       { Wg = w1;  outw = wf1;  KT = 8; f = b; }
    else if (b < 96)  { Wg = gw1; outw = wfg1; KT = 4; f = b - 64; }
    else if (b < 128) { Wg = gw2; outw = wfg2; KT = 4; f = b - 96; }
    else              { Wg = gw3; outw = wfg3; KT = 4; f = b - 128; }
    int kt = f >> 3, ct = f & 7;
    int k0 = kt * 32 + (l >> 4) * 8;
    int c = ct * 16 + (l & 15);
    f16x8 hi, lo;
    #pragma unroll
    for (int j = 0; j < 8; j++) {
        float w = Wg[(size_t)(k0 + j) * H + c];
        _Float16 hh = (_Float16)w;
        hi[j] = hh;
        lo[j] = (_Float16)(w - (float)hh);
    }
    *reinterpret_cast<f16x8*>(outw + ((size_t)f * 64 + l) * 8) = hi;
    *reinterpret_cast<f16x8*>(outw + ((size_t)KT * 8 * 64 * 8) + ((size_t)f * 64 + l) * 8) = lo;
}

// ---------------- Linear via fp16-split MFMA + LDS-staged B-frags ----------------
// B-frags double-buffered in LDS (16 KB per kt-chunk: hi 8KB + lo 8KB), staged
// via reg-loads + ds_write_b128 (per-lane contiguous, conflict-free). One
// barrier per kt; prefetch kt+1 overlaps compute of kt. A-path unchanged.
// OMODE 0: fp32 out.  OMODE 1: fp16 out scaled by dis[r].  POOL: fused mean-pool.

template <int K, bool LN, int OMODE, bool POOL>
__launch_bounds__(256)
__global__ void mfma_linear(const float* __restrict__ A, const _Float16* __restrict__ Wf,
                            const float* __restrict__ bias,
                            const float* __restrict__ ln_g, const float* __restrict__ ln_b,
                            const float* __restrict__ dis, const int* __restrict__ batch,
                            void* __restrict__ outp) {
    constexpr int KT = K / 32;
    __shared__ __align__(16) _Float16 stage[2][8192];   // [buf][hi 4096 | lo 4096] f16
    int t = threadIdx.x;
    int wv = t >> 6, l = t & 63;
    int lm = l & 15, lg = l >> 4;
    int rowBase = blockIdx.x * 64;
    int arow = rowBase + wv * 16 + lm;
    int arc = min(arow, NN - 1);
    const f16x8* __restrict__ BhG = reinterpret_cast<const f16x8*>(Wf);
    const f16x8* __restrict__ BlG = BhG + KT * 8 * 64;

    // stage one kt-chunk (8 frags x 64 lanes x f16x8 = 4096 f16 each of hi/lo)
    auto stage_kt = [&](int b, int kt) {
        f16x8* dstH = reinterpret_cast<f16x8*>(&stage[b][0]);
        f16x8* dstL = reinterpret_cast<f16x8*>(&stage[b][4096]);
        int wo = wv * 128 + l;               // f16x8 units; wave covers 128
        #pragma unroll
        for (int i = 0; i < 2; i++) {
            int o = wo + i * 64;
            dstH[o] = BhG[(size_t)kt * 512 + o];
            dstL[o] = BlG[(size_t)kt * 512 + o];
        }
    };

    f32x4 acc[8];
    #pragma unroll
    for (int ct = 0; ct < 8; ct++) acc[ct] = (f32x4){0.f, 0.f, 0.f, 0.f};

    stage_kt(0, 0);
    __syncthreads();
    int buf = 0;
    for (int kt = 0; kt < KT; kt++) {
        if (kt + 1 < KT) stage_kt(buf ^ 1, kt + 1);   // prefetch overlaps compute
        const float* ap = A + (size_t)arc * K + kt * 32 + lg * 8;
        float4 a0 = *(const float4*)ap;
        float4 a1 = *(const float4*)(ap + 4);
        float av[8] = {a0.x, a0.y, a0.z, a0.w, a1.x, a1.y, a1.z, a1.w};
        f16x8 ah, al;
        #pragma unroll
        for (int j = 0; j < 8; j++) {
            _Float16 hh = (_Float16)av[j];
            ah[j] = hh;
            al[j] = (_Float16)(av[j] - (float)hh);
        }
        #pragma unroll
        for (int ct = 0; ct < 8; ct++) {
            f16x8 bh = *reinterpret_cast<const f16x8*>(&stage[buf][(ct * 64 + l) * 8]);
            f16x8 bl = *reinterpret_cast<const f16x8*>(&stage[buf][4096 + (ct * 64 + l) * 8]);
            acc[ct] = __builtin_amdgcn_mfma_f32_16x16x32_f16(ah, bh, acc[ct], 0, 0, 0);
            acc[ct] = __builtin_amdgcn_mfma_f32_16x16x32_f16(ah, bl, acc[ct], 0, 0, 0);
            acc[ct] = __builtin_amdgcn_mfma_f32_16x16x32_f16(al, bh, acc[ct], 0, 0, 0);
        }
        __syncthreads();       // prefetch written; all waves done reading buf
        buf ^= 1;
    }

    float bv[8], gv[8], lbv[8];
    #pragma unroll
    for (int ct = 0; ct < 8; ct++) {
        int c = ct * 16 + lm;
        bv[ct] = bias[c];
        if constexpr (LN) { gv[ct] = ln_g[c]; lbv[ct] = ln_b[c]; }
    }

    float vals[4][8];
    #pragma unroll
    for (int q = 0; q < 4; q++) {
        float s = 0.f, sq = 0.f;
        #pragma unroll
        for (int ct = 0; ct < 8; ct++) {
            float v = fmaxf(acc[ct][q] + bv[ct], 0.f);
            vals[q][ct] = v;
            s += v; sq += v * v;
        }
        if constexpr (LN) {
            #pragma unroll
            for (int m = 1; m < 16; m <<= 1) {
                s  += __shfl_xor(s,  m, 64);
                sq += __shfl_xor(sq, m, 64);
            }
            float mean = s * (1.f / 128.f);
            float var  = sq * (1.f / 128.f) - mean * mean;
            float inv  = rsqrtf(var + 1e-5f);
            #pragma unroll
            for (int ct = 0; ct < 8; ct++)
                vals[q][ct] = (vals[q][ct] - mean) * inv * gv[ct] + lbv[ct];
        }
    }

    if constexpr (POOL) {
        __shared__ float tile[64][129];
        __shared__ int bl64[64];
        float* psums = (float*)outp;
        #pragma unroll
        for (int q = 0; q < 4; q++) {
            int r64 = wv * 16 + lg * 4 + q;
            #pragma unroll
            for (int ct = 0; ct < 8; ct++)
                tile[r64][ct * 16 + lm] = vals[q][ct];
        }
        if (t < 64) bl64[t] = batch[min(rowBase + t, NN - 1)];
        __syncthreads();
        if (t < H) {
            float pacc = 0.f;
            int curb = bl64[0];
            int rmax = min(64, NN - rowBase);
            for (int r = 0; r < rmax; r++) {
                int b = bl64[r];
                if (b != curb) {
                    atomicAdd(&psums[curb * H + t], pacc);
                    pacc = 0.f; curb = b;
                }
                pacc += tile[r][t];
            }
            atomicAdd(&psums[curb * H + t], pacc);
        }
    } else {
        #pragma unroll
        for (int q = 0; q < 4; q++) {
            int rr = rowBase + wv * 16 + lg * 4 + q;
            if (rr < NN) {
                if constexpr (OMODE == 1) {
                    _Float16* o16 = (_Float16*)outp;
                    float sc = dis[rr];
                    #pragma unroll
                    for (int ct = 0; ct < 8; ct++)
                        o16[(size_t)rr * H + ct * 16 + lm] = (_Float16)(vals[q][ct] * sc);
                } else {
                    float* o32 = (float*)outp;
                    #pragma unroll
                    for (int ct = 0; ct < 8; ct++)
                        o32[(size_t)rr * H + ct * 16 + lm] = vals[q][ct];
                }
            }
        }
    }
}

// ---------------- GCN aggregation: fp16 gather, fp32 accumulate ----------------

__launch_bounds__(256)
__global__ void agg_kernel(const _Float16* __restrict__ g16, const int* __restrict__ offs,
                           const int* __restrict__ degcnt, const int* __restrict__ csr,
                           const float* __restrict__ dis, float* __restrict__ out) {
    __shared__ int idx[8][64];
    int grp = threadIdx.x >> 5;        // 0..7
    int l = threadIdx.x & 31;
    int v = blockIdx.x * 8 + grp;      // grid exact: NN/8 blocks
    int beg = offs[v], cnt = degcnt[v];
    idx[grp][l]      = (l      < cnt) ? csr[beg + l]      : v;
    idx[grp][l + 32] = (l + 32 < cnt) ? csr[beg + l + 32] : v;

    const f16x4* __restrict__ G = reinterpret_cast<const f16x4*>(g16);  // 32 f16x4/row
    float dv = dis[v];
    f16x4 gvh = G[(size_t)v * 32 + l];
    float4 gv = make_float4((float)gvh[0], (float)gvh[1], (float)gvh[2], (float)gvh[3]);
    float4 acc = gv;                       // self term
    int n0 = min(cnt, 64);
    int m0 = (n0 + 7) & ~7;                // padded trip count

    for (int i = 0; i < m0; i += 8) {
        f16x4 tv[8];
        #pragma unroll
        for (int jj = 0; jj < 8; jj++)
            tv[jj] = G[(size_t)idx[grp][i + jj] * 32 + l];
        #pragma unroll
        for (int jj = 0; jj < 8; jj++) {
            acc.x += (float)tv[jj][0];
            acc.y += (float)tv[jj][1];
            acc.z += (float)tv[jj][2];
            acc.w += (float)tv[jj][3];
        }
    }
    float pad = (float)(m0 - n0);          // remove padded copies of g16[v]
    acc.x -= pad * gv.x; acc.y -= pad * gv.y;
    acc.z -= pad * gv.z; acc.w -= pad * gv.w;

    for (int i = 64; i < cnt; i++) {       // degree > 64 tail (essentially never)
        f16x4 a = G[(size_t)csr[beg + i] * 32 + l];
        acc.x += (float)a[0]; acc.y += (float)a[1];
        acc.z += (float)a[2]; acc.w += (float)a[3];
    }
    float4 o;
    o.x = dv * acc.x; o.y = dv * acc.y; o.z = dv * acc.z; o.w = dv * acc.w;
    reinterpret_cast<float4*>(out)[(size_t)v * 32 + l] = o;
}

// ---------------- memory K/V projection ----------------

__global__ void kv_kernel(const float* __restrict__ mb, const float* __restrict__ ipw,
                          const float* __restrict__ ipb,
                          float* __restrict__ kbuf, float* __restrict__ vbuf) {
    __shared__ float rowv[H];
    int m = blockIdx.x, i = threadIdx.x;
    rowv[i] = mb[m * H + i];
    __syncthreads();
    float ak = 0.f, av = 0.f;
    for (int j = 0; j < H; j++) {
        float x = rowv[j];
        ak = fmaf(x, ipw[(size_t)(H + i) * H + j], ak);
        av = fmaf(x, ipw[(size_t)(2 * H + i) * H + j], av);
    }
    kbuf[m * H + i] = ak + ipb[H + i];
    vbuf[m * H + i] = av + ipb[2 * H + i];
}

// ---------------- attention + classifier (one block per graph) ----------------

__launch_bounds__(128)
__global__ void attn_kernel(const float* __restrict__ psums, const int* __restrict__ gstart,
                            const float* __restrict__ kbuf, const float* __restrict__ vbuf,
                            const float* __restrict__ ipw, const float* __restrict__ ipb,
                            const float* __restrict__ out_w, const float* __restrict__ out_b,
                            const float* __restrict__ cw1, const float* __restrict__ cb1,
                            const float* __restrict__ cw2, const float* __restrict__ cb2,
                            float* __restrict__ out) {
    __shared__ float pooled[H], q[H], attn[H], z[2 * H], c1[H], sc[NHEAD * MM];
    int b = blockIdx.x, t = threadIdx.x;
    float cn = (float)max(gstart[b + 1] - gstart[b], 1);
    float pv = psums[b * H + t] / cn;
    pooled[t] = pv;
    z[t] = pv;
    __syncthreads();
    float a = 0.f;
    for (int j = 0; j < H; j++) a = fmaf(pooled[j], ipw[(size_t)t * H + j], a);
    q[t] = a + ipb[t];
    __syncthreads();
    for (int sidx = t; sidx < NHEAD * MM; sidx += 128) {
        int hh = sidx >> 6, m = sidx & 63;
        float s2 = 0.f;
        for (int d = 0; d < HDIM; d++)
            s2 = fmaf(q[hh * HDIM + d], kbuf[m * H + hh * HDIM + d], s2);
        sc[sidx] = s2 * 0.25f;   // 1/sqrt(16)
    }
    __syncthreads();
    if (t < NHEAD) {
        float mx = -1e30f;
        for (int m = 0; m < MM; m++) mx = fmaxf(mx, sc[t * MM + m]);
        float ssum = 0.f;
        for (int m = 0; m < MM; m++) { float e = expf(sc[t * MM + m] - mx); sc[t * MM + m] = e; ssum += e; }
        float inv = 1.f / ssum;
        for (int m = 0; m < MM; m++) sc[t * MM + m] *= inv;
    }
    __syncthreads();
    {
        int hh = t >> 4;
        float a2 = 0.f;
        for (int m = 0; m < MM; m++) a2 = fmaf(sc[hh * MM + m], vbuf[m * H + t], a2);
        attn[t] = a2;
    }
    __syncthreads();
    float mm = 0.f;
    for (int j = 0; j < H; j++) mm = fmaf(attn[j], out_w[(size_t)t * H + j], mm);
    z[H + t] = mm + out_b[t];
    __syncthreads();
    float cc = 0.f;
    for (int j = 0; j < 2 * H; j++) cc = fmaf(z[j], cw1[(size_t)j * H + t], cc);
    c1[t] = fmaxf(cc + cb1[t], 0.f);
    __syncthreads();
    if (t < CC) {
        float o = 0.f;
        for (int j = 0; j < H; j++) o = fmaf(c1[j], cw2[j * CC + t], o);
        out[b * CC + t] = o + cb2[t];
    }
}

// ---------------- launch ----------------

extern "C" void kernel_launch(void* const* d_in, const int* in_sizes, int n_in,
                              void* d_out, int out_size, void* d_ws, size_t ws_size,
                              hipStream_t stream) {
    const float* x      = (const float*)d_in[0];
    const int*   eidx   = (const int*)d_in[1];
    const int*   batch  = (const int*)d_in[2];
    const float* w1     = (const float*)d_in[3];
    const float* b1     = (const float*)d_in[4];
    const float* ln_g   = (const float*)d_in[5];
    const float* ln_b   = (const float*)d_in[6];
    const float* gw1    = (const float*)d_in[7];
    const float* gb1    = (const float*)d_in[8];
    const float* gw2    = (const float*)d_in[9];
    const float* gb2    = (const float*)d_in[10];
    const float* gw3    = (const float*)d_in[11];
    const float* gb3    = (const float*)d_in[12];
    const float* memb   = (const float*)d_in[13];
    const float* ipw    = (const float*)d_in[14];
    const float* ipb    = (const float*)d_in[15];
    const float* out_w  = (const float*)d_in[16];
    const float* out_b  = (const float*)d_in[17];
    const float* cw1    = (const float*)d_in[18];
    const float* cb1    = (const float*)d_in[19];
    const float* cw2    = (const float*)d_in[20];
    const float* cb2    = (const float*)d_in[21];

    const int* row = eidx;
    const int* col = eidx + EE;

    char* ws = (char*)d_ws;
    size_t off = 0;
    auto alloc = [&](size_t bytes) -> void* {
        void* p = ws + off;
        off += (bytes + 255) & ~(size_t)255;
        return p;
    };
    float* h_tmp  = (float*)alloc((size_t)NN * H * 4);
    _Float16* g16 = (_Float16*)alloc((size_t)NN * H * 2);
    char*  zbeg   = ws + off;
    float* psums  = (float*)alloc((size_t)BB * H * 4);
    size_t zbytes = (size_t)((ws + off) - zbeg);
    int*   degcnt = (int*)alloc((size_t)NN * 4);
    float* dis    = (float*)alloc((size_t)NN * 4);
    int*   offs   = (int*)alloc((size_t)NN * 4);
    int*   csr    = (int*)alloc((size_t)EE * 4);
    int2*  ebuf   = (int2*)alloc((size_t)EE * 8);
    int*   bcnt   = (int*)alloc((size_t)NRW * NSB * 4);
    int*   sbase  = (int*)alloc((size_t)NRW * NSB * 4);
    int*   rbase  = (int*)alloc(256);
    int*   gstart = (int*)alloc((size_t)(BB + 1) * 4);
    float* kbuf   = (float*)alloc((size_t)MM * H * 4);
    float* vbuf   = (float*)alloc((size_t)MM * H * 4);
    _Float16* wf1 = (_Float16*)alloc((size_t)2 * DIN * H * 2);   // 256 KB (hi+lo)
    _Float16* wfg1 = (_Float16*)alloc((size_t)2 * H * H * 2);    // 128 KB
    _Float16* wfg2 = (_Float16*)alloc((size_t)2 * H * H * 2);
    _Float16* wfg3 = (_Float16*)alloc((size_t)2 * H * H * 2);
    (void)ws_size; (void)in_sizes; (void)n_in; (void)out_size;

    hipMemsetAsync(zbeg, 0, zbytes, stream);   // psums

    // CSR build: fully-parallel two-level counting sort
    ecount<<<NSB, 256, 0, stream>>>(col, bcnt);
    escan<<<1, 64, 0, stream>>>(bcnt, sbase, rbase);
    escatter<<<NSB, 256, 0, stream>>>(row, col, sbase, ebuf);
    csr_build<<<NRW, 512, 0, stream>>>(ebuf, rbase, degcnt, offs, dis, csr);

    graph_bounds<<<(NN + 255) / 256, 256, 0, stream>>>(batch, gstart);

    // W-split precompute: one launch for all 4 weights
    wsplit_all<<<160, 64, 0, stream>>>(w1, gw1, gw2, gw3, wf1, wfg1, wfg2, wfg3);

    const int LGRID = (NN + 63) / 64;   // 782
    const int AGRID = NN / 8;           // 6250 (exact)

    // feature transform -> g1 (fp16, dis-scaled)
    mfma_linear<DIN, true, 1, false><<<LGRID, 256, 0, stream>>>(x, wf1, b1, ln_g, ln_b, dis, nullptr, g16);

    // GCN layer 1
    agg_kernel<<<AGRID, 256, 0, stream>>>(g16, offs, degcnt, csr, dis, h_tmp);
    mfma_linear<H, false, 1, false><<<LGRID, 256, 0, stream>>>(h_tmp, wfg1, gb1, nullptr, nullptr, dis, nullptr, g16);
    // GCN layer 2
    agg_kernel<<<AGRID, 256, 0, stream>>>(g16, offs, degcnt, csr, dis, h_tmp);
    mfma_linear<H, false, 1, false><<<LGRID, 256, 0, stream>>>(h_tmp, wfg2, gb2, nullptr, nullptr, dis, nullptr, g16);
    // GCN layer 3: fused mean-pool epilogue
    agg_kernel<<<AGRID, 256, 0, stream>>>(g16, offs, degcnt, csr, dis, h_tmp);
    mfma_linear<H, false, 0, true><<<LGRID, 256, 0, stream>>>(h_tmp, wfg3, gb3, nullptr, nullptr, dis, batch, psums);

    kv_kernel<<<MM, H, 0, stream>>>(memb, ipw, ipb, kbuf, vbuf);
    attn_kernel<<<BB, H, 0, stream>>>(psums, gstart, kbuf, vbuf, ipw, ipb, out_w, out_b,
                                      cw1, cb1, cw2, cb2, (float*)d_out);
}

// Round 17
// 254.399 us; speedup vs baseline: 1.2725x; 1.0582x over previous
//
#include <hip/hip_runtime.h>

#define NN 50000
#define EE 800000
#define DIN 256
#define H 128
#define MM 64
#define CC 4
#define BB 128
#define NHEAD 8
#define HDIM 16

#define NRW 50          // node ranges (1000 nodes each)
#define RNODES 1000
#define NSB 625         // edge-slice blocks
#define ESL 1280        // edges per slice block (NSB*ESL == EE)

typedef _Float16 f16x8 __attribute__((ext_vector_type(8)));
typedef _Float16 f16x4 __attribute__((ext_vector_type(4)));
typedef float f32x4 __attribute__((ext_vector_type(4)));

// ---------------- CSR build: two-level counting sort ----------------

__launch_bounds__(256)
__global__ void ecount(const int* __restrict__ col, int* __restrict__ bcnt) {
    __shared__ int hist[NRW];
    int b = blockIdx.x, t = threadIdx.x;
    if (t < NRW) hist[t] = 0;
    __syncthreads();
    int e0 = b * ESL;
    #pragma unroll
    for (int i = 0; i < ESL / 256; i++) {
        int c = col[e0 + t + i * 256];
        atomicAdd(&hist[c / RNODES], 1);
    }
    __syncthreads();
    if (t < NRW) bcnt[t * NSB + b] = hist[t];
}

__global__ void escan(const int* __restrict__ bcnt, int* __restrict__ sbase,
                      int* __restrict__ rbase) {
    __shared__ int rt[NRW];
    int t = threadIdx.x;
    if (t < NRW) {
        int s = 0;
        for (int b = 0; b < NSB; b++) s += bcnt[t * NSB + b];
        rt[t] = s;
    }
    __syncthreads();
    if (t == 0) {
        int run = 0;
        for (int r = 0; r < NRW; r++) { rbase[r] = run; run += rt[r]; }
    }
    __syncthreads();
    if (t < NRW) {
        int run = rbase[t];
        for (int b = 0; b < NSB; b++) { sbase[t * NSB + b] = run; run += bcnt[t * NSB + b]; }
    }
}

__launch_bounds__(256)
__global__ void escatter(const int* __restrict__ row, const int* __restrict__ col,
                         const int* __restrict__ sbase, int2* __restrict__ ebuf) {
    __shared__ int cur[NRW];
    int b = blockIdx.x, t = threadIdx.x;
    if (t < NRW) cur[t] = sbase[t * NSB + b];
    __syncthreads();
    int e0 = b * ESL;
    #pragma unroll
    for (int i = 0; i < ESL / 256; i++) {
        int e = e0 + t + i * 256;
        int c = col[e];
        int u = row[e];
        int r = c / RNODES;
        int p = atomicAdd(&cur[r], 1);
        ebuf[p] = make_int2(u, c - r * RNODES);
    }
}

__launch_bounds__(512)
__global__ void csr_build(const int2* __restrict__ ebuf, const int* __restrict__ rbase,
                          int* __restrict__ degcnt, int* __restrict__ offs,
                          float* __restrict__ dis, int* __restrict__ csr) {
    __shared__ int hist[RNODES];
    __shared__ int cur[RNODES];
    __shared__ int sb[512];
    int r = blockIdx.x, t = threadIdx.x;
    int r0 = r * RNODES;
    int rb = rbase[r];
    int re = (r + 1 < NRW) ? rbase[r + 1] : EE;
    for (int i = t; i < RNODES; i += 512) hist[i] = 0;
    __syncthreads();
    for (int e = rb + t; e < re; e += 512) atomicAdd(&hist[ebuf[e].y], 1);
    __syncthreads();
    int i0 = 2 * t, i1 = 2 * t + 1;
    int d0 = (i0 < RNODES) ? hist[i0] : 0;
    int d1 = (i1 < RNODES) ? hist[i1] : 0;
    int ps = d0 + d1;
    sb[t] = ps;
    __syncthreads();
    for (int off = 1; off < 512; off <<= 1) {
        int x = (t >= off) ? sb[t - off] : 0;
        __syncthreads();
        sb[t] += x;
        __syncthreads();
    }
    int excl = sb[t] - ps;
    if (i0 < RNODES) {
        cur[i0] = excl;
        degcnt[r0 + i0] = d0;
        offs[r0 + i0] = rb + excl;
        dis[r0 + i0] = rsqrtf((float)(d0 + 1));
    }
    if (i1 < RNODES) {
        cur[i1] = excl + d0;
        degcnt[r0 + i1] = d1;
        offs[r0 + i1] = rb + excl + d0;
        dis[r0 + i1] = rsqrtf((float)(d1 + 1));
    }
    __syncthreads();
    for (int e = rb + t; e < re; e += 512) {
        int2 ed = ebuf[e];
        int p = atomicAdd(&cur[ed.y], 1);
        csr[rb + p] = ed.x;
    }
}

// ---------------- graph boundaries (batch is sorted) ----------------

__global__ void graph_bounds(const int* __restrict__ batch, int* __restrict__ gstart) {
    int v = blockIdx.x * blockDim.x + threadIdx.x;
    if (v >= NN) return;
    int b = batch[v];
    if (v == 0) {
        for (int g = 0; g <= b; g++) gstart[g] = 0;
    } else {
        int pb = batch[v - 1];
        for (int g = pb + 1; g <= b; g++) gstart[g] = v;
    }
    if (v == NN - 1) {
        for (int g = b + 1; g <= BB; g++) gstart[g] = NN;
    }
}

// ---------------- W split to frag-ordered fp16 hi/lo (one launch, all 4 weights) -------

__global__ void wsplit_all(const float* __restrict__ w1, const float* __restrict__ gw1,
                           const float* __restrict__ gw2, const float* __restrict__ gw3,
                           _Float16* __restrict__ wf1, _Float16* __restrict__ wfg1,
                           _Float16* __restrict__ wfg2, _Float16* __restrict__ wfg3) {
    int b = blockIdx.x;
    int l = threadIdx.x;          // 0..63
    const float* Wg; _Float16* outw; int KT, f;
    if (b < 64)       { Wg = w1;  outw = wf1;  KT = 8; f = b; }
    else if (b < 96)  { Wg = gw1; outw = wfg1; KT = 4; f = b - 64; }
    else if (b < 128) { Wg = gw2; outw = wfg2; KT = 4; f = b - 96; }
    else              { Wg = gw3; outw = wfg3; KT = 4; f = b - 128; }
    int kt = f >> 3, ct = f & 7;
    int k0 = kt * 32 + (l >> 4) * 8;
    int c = ct * 16 + (l & 15);
    f16x8 hi, lo;
    #pragma unroll
    for (int j = 0; j < 8; j++) {
        float w = Wg[(size_t)(k0 + j) * H + c];
        _Float16 hh = (_Float16)w;
        hi[j] = hh;
        lo[j] = (_Float16)(w - (float)hh);
    }
    *reinterpret_cast<f16x8*>(outw + ((size_t)f * 64 + l) * 8) = hi;
    *reinterpret_cast<f16x8*>(outw + ((size_t)KT * 8 * 64 * 8) + ((size_t)f * 64 + l) * 8) = lo;
}

// ---------------- Linear via fp16-split MFMA + LDS-staged B-frags ----------------
// B-frags double-buffered in LDS (reg-stage + ds_write_b128). A-chunk prefetched
// one kt ahead (regs). AIN 0: fp32 A, 3-pass split. AIN 1: fp16 A, 2-pass.
// OMODE 0: fp32 out.  OMODE 1: fp16 out scaled by dis[r].  POOL: fused mean-pool.

template <int K, bool LN, int OMODE, bool POOL, int AIN>
__launch_bounds__(256)
__global__ void mfma_linear(const void* __restrict__ Ap, const _Float16* __restrict__ Wf,
                            const float* __restrict__ bias,
                            const float* __restrict__ ln_g, const float* __restrict__ ln_b,
                            const float* __restrict__ dis, const int* __restrict__ batch,
                            void* __restrict__ outp) {
    constexpr int KT = K / 32;
    __shared__ __align__(16) _Float16 stage[2][8192];   // [buf][hi 4096 | lo 4096] f16
    int t = threadIdx.x;
    int wv = t >> 6, l = t & 63;
    int lm = l & 15, lg = l >> 4;
    int rowBase = blockIdx.x * 64;
    int arow = rowBase + wv * 16 + lm;
    int arc = min(arow, NN - 1);
    const float* A32 = (const float*)Ap;
    const _Float16* A16 = (const _Float16*)Ap;
    const f16x8* __restrict__ BhG = reinterpret_cast<const f16x8*>(Wf);
    const f16x8* __restrict__ BlG = BhG + KT * 8 * 64;

    auto stage_kt = [&](int b, int kt) {
        f16x8* dstH = reinterpret_cast<f16x8*>(&stage[b][0]);
        f16x8* dstL = reinterpret_cast<f16x8*>(&stage[b][4096]);
        int wo = wv * 128 + l;
        #pragma unroll
        for (int i = 0; i < 2; i++) {
            int o = wo + i * 64;
            dstH[o] = BhG[(size_t)kt * 512 + o];
            dstL[o] = BlG[(size_t)kt * 512 + o];
        }
    };

    f32x4 acc[8];
    #pragma unroll
    for (int ct = 0; ct < 8; ct++) acc[ct] = (f32x4){0.f, 0.f, 0.f, 0.f};

    stage_kt(0, 0);
    // prefetch A chunk 0 into regs
    float4 a0c = {}, a1c = {}; f16x8 a16c = {};
    if constexpr (AIN == 0) {
        const float* ap = A32 + (size_t)arc * K + lg * 8;
        a0c = *(const float4*)ap; a1c = *(const float4*)(ap + 4);
    } else {
        a16c = *(const f16x8*)(A16 + (size_t)arc * K + lg * 8);
    }
    __syncthreads();
    int buf = 0;
    for (int kt = 0; kt < KT; kt++) {
        float4 a0n = {}, a1n = {}; f16x8 a16n = {};
        if (kt + 1 < KT) {
            stage_kt(buf ^ 1, kt + 1);           // B prefetch -> LDS
            if constexpr (AIN == 0) {            // A prefetch -> regs
                const float* ap = A32 + (size_t)arc * K + (kt + 1) * 32 + lg * 8;
                a0n = *(const float4*)ap; a1n = *(const float4*)(ap + 4);
            } else {
                a16n = *(const f16x8*)(A16 + (size_t)arc * K + (kt + 1) * 32 + lg * 8);
            }
        }
        f16x8 ah, al;
        if constexpr (AIN == 0) {
            float av[8] = {a0c.x, a0c.y, a0c.z, a0c.w, a1c.x, a1c.y, a1c.z, a1c.w};
            #pragma unroll
            for (int j = 0; j < 8; j++) {
                _Float16 hh = (_Float16)av[j];
                ah[j] = hh;
                al[j] = (_Float16)(av[j] - (float)hh);
            }
        } else {
            ah = a16c;
        }
        #pragma unroll
        for (int ct = 0; ct < 8; ct++) {
            f16x8 bh = *reinterpret_cast<const f16x8*>(&stage[buf][(ct * 64 + l) * 8]);
            f16x8 bl = *reinterpret_cast<const f16x8*>(&stage[buf][4096 + (ct * 64 + l) * 8]);
            acc[ct] = __builtin_amdgcn_mfma_f32_16x16x32_f16(ah, bh, acc[ct], 0, 0, 0);
            acc[ct] = __builtin_amdgcn_mfma_f32_16x16x32_f16(ah, bl, acc[ct], 0, 0, 0);
            if constexpr (AIN == 0)
                acc[ct] = __builtin_amdgcn_mfma_f32_16x16x32_f16(al, bh, acc[ct], 0, 0, 0);
        }
        __syncthreads();
        buf ^= 1;
        a0c = a0n; a1c = a1n; a16c = a16n;
    }

    float bv[8], gv[8], lbv[8];
    #pragma unroll
    for (int ct = 0; ct < 8; ct++) {
        int c = ct * 16 + lm;
        bv[ct] = bias[c];
        if constexpr (LN) { gv[ct] = ln_g[c]; lbv[ct] = ln_b[c]; }
    }

    float vals[4][8];
    #pragma unroll
    for (int q = 0; q < 4; q++) {
        float s = 0.f, sq = 0.f;
        #pragma unroll
        for (int ct = 0; ct < 8; ct++) {
            float v = fmaxf(acc[ct][q] + bv[ct], 0.f);
            vals[q][ct] = v;
            s += v; sq += v * v;
        }
        if constexpr (LN) {
            #pragma unroll
            for (int m = 1; m < 16; m <<= 1) {
                s  += __shfl_xor(s,  m, 64);
                sq += __shfl_xor(sq, m, 64);
            }
            float mean = s * (1.f / 128.f);
            float var  = sq * (1.f / 128.f) - mean * mean;
            float inv  = rsqrtf(var + 1e-5f);
            #pragma unroll
            for (int ct = 0; ct < 8; ct++)
                vals[q][ct] = (vals[q][ct] - mean) * inv * gv[ct] + lbv[ct];
        }
    }

    if constexpr (POOL) {
        __shared__ float tile[64][129];
        __shared__ int bl64[64];
        float* psums = (float*)outp;
        #pragma unroll
        for (int q = 0; q < 4; q++) {
            int r64 = wv * 16 + lg * 4 + q;
            #pragma unroll
            for (int ct = 0; ct < 8; ct++)
                tile[r64][ct * 16 + lm] = vals[q][ct];
        }
        if (t < 64) bl64[t] = batch[min(rowBase + t, NN - 1)];
        __syncthreads();
        if (t < H) {
            float pacc = 0.f;
            int curb = bl64[0];
            int rmax = min(64, NN - rowBase);
            for (int r = 0; r < rmax; r++) {
                int b = bl64[r];
                if (b != curb) {
                    atomicAdd(&psums[curb * H + t], pacc);
                    pacc = 0.f; curb = b;
                }
                pacc += tile[r][t];
            }
            atomicAdd(&psums[curb * H + t], pacc);
        }
    } else {
        #pragma unroll
        for (int q = 0; q < 4; q++) {
            int rr = rowBase + wv * 16 + lg * 4 + q;
            if (rr < NN) {
                if constexpr (OMODE == 1) {
                    _Float16* o16 = (_Float16*)outp;
                    float sc = dis[rr];
                    #pragma unroll
                    for (int ct = 0; ct < 8; ct++)
                        o16[(size_t)rr * H + ct * 16 + lm] = (_Float16)(vals[q][ct] * sc);
                } else {
                    float* o32 = (float*)outp;
                    #pragma unroll
                    for (int ct = 0; ct < 8; ct++)
                        o32[(size_t)rr * H + ct * 16 + lm] = vals[q][ct];
                }
            }
        }
    }
}

// ---------------- GCN aggregation: fp16 gather, fp32 accumulate, fp16 out ----------------

__launch_bounds__(256)
__global__ void agg_kernel(const _Float16* __restrict__ g16, const int* __restrict__ offs,
                           const int* __restrict__ degcnt, const int* __restrict__ csr,
                           const float* __restrict__ dis, _Float16* __restrict__ out16) {
    __shared__ int idx[8][64];
    int grp = threadIdx.x >> 5;        // 0..7
    int l = threadIdx.x & 31;
    int v = blockIdx.x * 8 + grp;      // grid exact: NN/8 blocks
    int beg = offs[v], cnt = degcnt[v];
    idx[grp][l]      = (l      < cnt) ? csr[beg + l]      : v;
    idx[grp][l + 32] = (l + 32 < cnt) ? csr[beg + l + 32] : v;

    const f16x4* __restrict__ G = reinterpret_cast<const f16x4*>(g16);  // 32 f16x4/row
    float dv = dis[v];
    f16x4 gvh = G[(size_t)v * 32 + l];
    float4 gv = make_float4((float)gvh[0], (float)gvh[1], (float)gvh[2], (float)gvh[3]);
    float4 acc = gv;                       // self term
    int n0 = min(cnt, 64);
    int m0 = (n0 + 7) & ~7;                // padded trip count

    for (int i = 0; i < m0; i += 8) {
        f16x4 tv[8];
        #pragma unroll
        for (int jj = 0; jj < 8; jj++)
            tv[jj] = G[(size_t)idx[grp][i + jj] * 32 + l];
        #pragma unroll
        for (int jj = 0; jj < 8; jj++) {
            acc.x += (float)tv[jj][0];
            acc.y += (float)tv[jj][1];
            acc.z += (float)tv[jj][2];
            acc.w += (float)tv[jj][3];
        }
    }
    float pad = (float)(m0 - n0);          // remove padded copies of g16[v]
    acc.x -= pad * gv.x; acc.y -= pad * gv.y;
    acc.z -= pad * gv.z; acc.w -= pad * gv.w;

    for (int i = 64; i < cnt; i++) {       // degree > 64 tail (essentially never)
        f16x4 a = G[(size_t)csr[beg + i] * 32 + l];
        acc.x += (float)a[0]; acc.y += (float)a[1];
        acc.z += (float)a[2]; acc.w += (float)a[3];
    }
    f16x4 o;
    o[0] = (_Float16)(dv * acc.x); o[1] = (_Float16)(dv * acc.y);
    o[2] = (_Float16)(dv * acc.z); o[3] = (_Float16)(dv * acc.w);
    reinterpret_cast<f16x4*>(out16)[(size_t)v * 32 + l] = o;
}

// ---------------- memory K/V projection ----------------

__global__ void kv_kernel(const float* __restrict__ mb, const float* __restrict__ ipw,
                          const float* __restrict__ ipb,
                          float* __restrict__ kbuf, float* __restrict__ vbuf) {
    __shared__ float rowv[H];
    int m = blockIdx.x, i = threadIdx.x;
    rowv[i] = mb[m * H + i];
    __syncthreads();
    float ak = 0.f, av = 0.f;
    for (int j = 0; j < H; j++) {
        float x = rowv[j];
        ak = fmaf(x, ipw[(size_t)(H + i) * H + j], ak);
        av = fmaf(x, ipw[(size_t)(2 * H + i) * H + j], av);
    }
    kbuf[m * H + i] = ak + ipb[H + i];
    vbuf[m * H + i] = av + ipb[2 * H + i];
}

// ---------------- attention + classifier (one block per graph) ----------------

__launch_bounds__(128)
__global__ void attn_kernel(const float* __restrict__ psums, const int* __restrict__ gstart,
                            const float* __restrict__ kbuf, const float* __restrict__ vbuf,
                            const float* __restrict__ ipw, const float* __restrict__ ipb,
                            const float* __restrict__ out_w, const float* __restrict__ out_b,
                            const float* __restrict__ cw1, const float* __restrict__ cb1,
                            const float* __restrict__ cw2, const float* __restrict__ cb2,
                            float* __restrict__ out) {
    __shared__ float pooled[H], q[H], attn[H], z[2 * H], c1[H], sc[NHEAD * MM];
    int b = blockIdx.x, t = threadIdx.x;
    float cn = (float)max(gstart[b + 1] - gstart[b], 1);
    float pv = psums[b * H + t] / cn;
    pooled[t] = pv;
    z[t] = pv;
    __syncthreads();
    float a = 0.f;
    for (int j = 0; j < H; j++) a = fmaf(pooled[j], ipw[(size_t)t * H + j], a);
    q[t] = a + ipb[t];
    __syncthreads();
    for (int sidx = t; sidx < NHEAD * MM; sidx += 128) {
        int hh = sidx >> 6, m = sidx & 63;
        float s2 = 0.f;
        for (int d = 0; d < HDIM; d++)
            s2 = fmaf(q[hh * HDIM + d], kbuf[m * H + hh * HDIM + d], s2);
        sc[sidx] = s2 * 0.25f;   // 1/sqrt(16)
    }
    __syncthreads();
    if (t < NHEAD) {
        float mx = -1e30f;
        for (int m = 0; m < MM; m++) mx = fmaxf(mx, sc[t * MM + m]);
        float ssum = 0.f;
        for (int m = 0; m < MM; m++) { float e = expf(sc[t * MM + m] - mx); sc[t * MM + m] = e; ssum += e; }
        float inv = 1.f / ssum;
        for (int m = 0; m < MM; m++) sc[t * MM + m] *= inv;
    }
    __syncthreads();
    {
        int hh = t >> 4;
        float a2 = 0.f;
        for (int m = 0; m < MM; m++) a2 = fmaf(sc[hh * MM + m], vbuf[m * H + t], a2);
        attn[t] = a2;
    }
    __syncthreads();
    float mm = 0.f;
    for (int j = 0; j < H; j++) mm = fmaf(attn[j], out_w[(size_t)t * H + j], mm);
    z[H + t] = mm + out_b[t];
    __syncthreads();
    float cc = 0.f;
    for (int j = 0; j < 2 * H; j++) cc = fmaf(z[j], cw1[(size_t)j * H + t], cc);
    c1[t] = fmaxf(cc + cb1[t], 0.f);
    __syncthreads();
    if (t < CC) {
        float o = 0.f;
        for (int j = 0; j < H; j++) o = fmaf(c1[j], cw2[j * CC + t], o);
        out[b * CC + t] = o + cb2[t];
    }
}

// ---------------- launch ----------------

extern "C" void kernel_launch(void* const* d_in, const int* in_sizes, int n_in,
                              void* d_out, int out_size, void* d_ws, size_t ws_size,
                              hipStream_t stream) {
    const float* x      = (const float*)d_in[0];
    const int*   eidx   = (const int*)d_in[1];
    const int*   batch  = (const int*)d_in[2];
    const float* w1     = (const float*)d_in[3];
    const float* b1     = (const float*)d_in[4];
    const float* ln_g   = (const float*)d_in[5];
    const float* ln_b   = (const float*)d_in[6];
    const float* gw1    = (const float*)d_in[7];
    const float* gb1    = (const float*)d_in[8];
    const float* gw2    = (const float*)d_in[9];
    const float* gb2    = (const float*)d_in[10];
    const float* gw3    = (const float*)d_in[11];
    const float* gb3    = (const float*)d_in[12];
    const float* memb   = (const float*)d_in[13];
    const float* ipw    = (const float*)d_in[14];
    const float* ipb    = (const float*)d_in[15];
    const float* out_w  = (const float*)d_in[16];
    const float* out_b  = (const float*)d_in[17];
    const float* cw1    = (const float*)d_in[18];
    const float* cb1    = (const float*)d_in[19];
    const float* cw2    = (const float*)d_in[20];
    const float* cb2    = (const float*)d_in[21];

    const int* row = eidx;
    const int* col = eidx + EE;

    char* ws = (char*)d_ws;
    size_t off = 0;
    auto alloc = [&](size_t bytes) -> void* {
        void* p = ws + off;
        off += (bytes + 255) & ~(size_t)255;
        return p;
    };
    _Float16* a16 = (_Float16*)alloc((size_t)NN * H * 2);   // agg output (fp16)
    _Float16* g16 = (_Float16*)alloc((size_t)NN * H * 2);   // gather array (fp16)
    char*  zbeg   = ws + off;
    float* psums  = (float*)alloc((size_t)BB * H * 4);
    size_t zbytes = (size_t)((ws + off) - zbeg);
    int*   degcnt = (int*)alloc((size_t)NN * 4);
    float* dis    = (float*)alloc((size_t)NN * 4);
    int*   offs   = (int*)alloc((size_t)NN * 4);
    int*   csr    = (int*)alloc((size_t)EE * 4);
    int2*  ebuf   = (int2*)alloc((size_t)EE * 8);
    int*   bcnt   = (int*)alloc((size_t)NRW * NSB * 4);
    int*   sbase  = (int*)alloc((size_t)NRW * NSB * 4);
    int*   rbase  = (int*)alloc(256);
    int*   gstart = (int*)alloc((size_t)(BB + 1) * 4);
    float* kbuf   = (float*)alloc((size_t)MM * H * 4);
    float* vbuf   = (float*)alloc((size_t)MM * H * 4);
    _Float16* wf1 = (_Float16*)alloc((size_t)2 * DIN * H * 2);   // 256 KB (hi+lo)
    _Float16* wfg1 = (_Float16*)alloc((size_t)2 * H * H * 2);    // 128 KB
    _Float16* wfg2 = (_Float16*)alloc((size_t)2 * H * H * 2);
    _Float16* wfg3 = (_Float16*)alloc((size_t)2 * H * H * 2);
    (void)ws_size; (void)in_sizes; (void)n_in; (void)out_size;

    hipMemsetAsync(zbeg, 0, zbytes, stream);   // psums

    // CSR build: fully-parallel two-level counting sort
    ecount<<<NSB, 256, 0, stream>>>(col, bcnt);
    escan<<<1, 64, 0, stream>>>(bcnt, sbase, rbase);
    escatter<<<NSB, 256, 0, stream>>>(row, col, sbase, ebuf);
    csr_build<<<NRW, 512, 0, stream>>>(ebuf, rbase, degcnt, offs, dis, csr);

    graph_bounds<<<(NN + 255) / 256, 256, 0, stream>>>(batch, gstart);

    // W-split precompute: one launch for all 4 weights
    wsplit_all<<<160, 64, 0, stream>>>(w1, gw1, gw2, gw3, wf1, wfg1, wfg2, wfg3);

    const int LGRID = (NN + 63) / 64;   // 782
    const int AGRID = NN / 8;           // 6250 (exact)

    // feature transform (fp32 A, 3-pass) -> g1 (fp16, dis-scaled)
    mfma_linear<DIN, true, 1, false, 0><<<LGRID, 256, 0, stream>>>(x, wf1, b1, ln_g, ln_b, dis, nullptr, g16);

    // GCN layer 1 (fp16 A, 2-pass)
    agg_kernel<<<AGRID, 256, 0, stream>>>(g16, offs, degcnt, csr, dis, a16);
    mfma_linear<H, false, 1, false, 1><<<LGRID, 256, 0, stream>>>(a16, wfg1, gb1, nullptr, nullptr, dis, nullptr, g16);
    // GCN layer 2
    agg_kernel<<<AGRID, 256, 0, stream>>>(g16, offs, degcnt, csr, dis, a16);
    mfma_linear<H, false, 1, false, 1><<<LGRID, 256, 0, stream>>>(a16, wfg2, gb2, nullptr, nullptr, dis, nullptr, g16);
    // GCN layer 3: fused mean-pool epilogue
    agg_kernel<<<AGRID, 256, 0, stream>>>(g16, offs, degcnt, csr, dis, a16);
    mfma_linear<H, false, 0, true, 1><<<LGRID, 256, 0, stream>>>(a16, wfg3, gb3, nullptr, nullptr, dis, batch, psums);

    kv_kernel<<<MM, H, 0, stream>>>(memb, ipw, ipb, kbuf, vbuf);
    attn_kernel<<<BB, H, 0, stream>>>(psums, gstart, kbuf, vbuf, ipw, ipb, out_w, out_b,
                                      cw1, cb1, cw2, cb2, (float*)d_out);
}

// Round 18
// 235.920 us; speedup vs baseline: 1.3722x; 1.0783x over previous
//
#include <hip/hip_runtime.h>

#define NN 50000
#define EE 800000
#define DIN 256
#define H 128
#define MM 64
#define CC 4
#define BB 128
#define NHEAD 8
#define HDIM 16

#define NRW 50          // node ranges (1000 nodes each)
#define RNODES 1000
#define NSB 625         // edge-slice blocks
#define ESL 1280        // edges per slice block (NSB*ESL == EE)

typedef _Float16 f16x8 __attribute__((ext_vector_type(8)));
typedef _Float16 f16x4 __attribute__((ext_vector_type(4)));
typedef float f32x4 __attribute__((ext_vector_type(4)));

// ---------------- CSR build: two-level counting sort ----------------

__launch_bounds__(256)
__global__ void ecount(const int* __restrict__ col, int* __restrict__ bcnt) {
    __shared__ int hist[NRW];
    int b = blockIdx.x, t = threadIdx.x;
    if (t < NRW) hist[t] = 0;
    __syncthreads();
    int e0 = b * ESL;
    #pragma unroll
    for (int i = 0; i < ESL / 256; i++) {
        int c = col[e0 + t + i * 256];
        atomicAdd(&hist[c / RNODES], 1);
    }
    __syncthreads();
    if (t < NRW) bcnt[t * NSB + b] = hist[t];
}

// per-range totals (parallel reduce; 50 blocks)
__launch_bounds__(256)
__global__ void erange_tot(const int* __restrict__ bcnt, int* __restrict__ rtot) {
    __shared__ int red[4];
    int r = blockIdx.x, t = threadIdx.x;
    int s = 0;
    for (int b = t; b < NSB; b += 256) s += bcnt[r * NSB + b];
    #pragma unroll
    for (int m = 1; m < 64; m <<= 1) s += __shfl_xor(s, m, 64);
    if ((t & 63) == 0) red[t >> 6] = s;
    __syncthreads();
    if (t == 0) rtot[r] = red[0] + red[1] + red[2] + red[3];
}

__global__ void rscan(const int* __restrict__ rtot, int* __restrict__ rbase) {
    if (threadIdx.x == 0 && blockIdx.x == 0) {
        int run = 0;
        for (int i = 0; i < NRW; i++) { rbase[i] = run; run += rtot[i]; }
    }
}

// per-range exclusive scan over slice blocks (chunked block-scan; 50 blocks)
__launch_bounds__(256)
__global__ void esbase(const int* __restrict__ bcnt, const int* __restrict__ rbase,
                       int* __restrict__ sbase) {
    __shared__ int sb[256];
    __shared__ int carry;
    int r = blockIdx.x, t = threadIdx.x;
    if (t == 0) carry = rbase[r];
    __syncthreads();
    for (int base = 0; base < NSB; base += 256) {
        int b = base + t;
        int v = (b < NSB) ? bcnt[r * NSB + b] : 0;
        sb[t] = v;
        __syncthreads();
        for (int off = 1; off < 256; off <<= 1) {
            int x = (t >= off) ? sb[t - off] : 0;
            __syncthreads();
            sb[t] += x;
            __syncthreads();
        }
        if (b < NSB) sbase[r * NSB + b] = carry + sb[t] - v;   // exclusive
        __syncthreads();
        if (t == 255) carry += sb[255];
        __syncthreads();
    }
}

__launch_bounds__(256)
__global__ void escatter(const int* __restrict__ row, const int* __restrict__ col,
                         const int* __restrict__ sbase, int2* __restrict__ ebuf) {
    __shared__ int cur[NRW];
    int b = blockIdx.x, t = threadIdx.x;
    if (t < NRW) cur[t] = sbase[t * NSB + b];
    __syncthreads();
    int e0 = b * ESL;
    #pragma unroll
    for (int i = 0; i < ESL / 256; i++) {
        int e = e0 + t + i * 256;
        int c = col[e];
        int u = row[e];
        int r = c / RNODES;
        int p = atomicAdd(&cur[r], 1);
        ebuf[p] = make_int2(u, c - r * RNODES);
    }
}

__launch_bounds__(512)
__global__ void csr_build(const int2* __restrict__ ebuf, const int* __restrict__ rbase,
                          int* __restrict__ degcnt, int* __restrict__ offs,
                          float* __restrict__ dis, int* __restrict__ csr) {
    __shared__ int hist[RNODES];
    __shared__ int cur[RNODES];
    __shared__ int sb[512];
    int r = blockIdx.x, t = threadIdx.x;
    int r0 = r * RNODES;
    int rb = rbase[r];
    int re = (r + 1 < NRW) ? rbase[r + 1] : EE;
    for (int i = t; i < RNODES; i += 512) hist[i] = 0;
    __syncthreads();
    for (int e = rb + t; e < re; e += 512) atomicAdd(&hist[ebuf[e].y], 1);
    __syncthreads();
    int i0 = 2 * t, i1 = 2 * t + 1;
    int d0 = (i0 < RNODES) ? hist[i0] : 0;
    int d1 = (i1 < RNODES) ? hist[i1] : 0;
    int ps = d0 + d1;
    sb[t] = ps;
    __syncthreads();
    for (int off = 1; off < 512; off <<= 1) {
        int x = (t >= off) ? sb[t - off] : 0;
        __syncthreads();
        sb[t] += x;
        __syncthreads();
    }
    int excl = sb[t] - ps;
    if (i0 < RNODES) {
        cur[i0] = excl;
        degcnt[r0 + i0] = d0;
        offs[r0 + i0] = rb + excl;
        dis[r0 + i0] = rsqrtf((float)(d0 + 1));
    }
    if (i1 < RNODES) {
        cur[i1] = excl + d0;
        degcnt[r0 + i1] = d1;
        offs[r0 + i1] = rb + excl + d0;
        dis[r0 + i1] = rsqrtf((float)(d1 + 1));
    }
    __syncthreads();
    for (int e = rb + t; e < re; e += 512) {
        int2 ed = ebuf[e];
        int p = atomicAdd(&cur[ed.y], 1);
        csr[rb + p] = ed.x;
    }
}

// ---------------- graph boundaries (batch is sorted) ----------------

__global__ void graph_bounds(const int* __restrict__ batch, int* __restrict__ gstart) {
    int v = blockIdx.x * blockDim.x + threadIdx.x;
    if (v >= NN) return;
    int b = batch[v];
    if (v == 0) {
        for (int g = 0; g <= b; g++) gstart[g] = 0;
    } else {
        int pb = batch[v - 1];
        for (int g = pb + 1; g <= b; g++) gstart[g] = v;
    }
    if (v == NN - 1) {
        for (int g = b + 1; g <= BB; g++) gstart[g] = NN;
    }
}

// ---------------- W split to frag-ordered fp16 hi/lo (one launch, all 4 weights) -------

__global__ void wsplit_all(const float* __restrict__ w1, const float* __restrict__ gw1,
                           const float* __restrict__ gw2, const float* __restrict__ gw3,
                           _Float16* __restrict__ wf1, _Float16* __restrict__ wfg1,
                           _Float16* __restrict__ wfg2, _Float16* __restrict__ wfg3) {
    int b = blockIdx.x;
    int l = threadIdx.x;          // 0..63
    const float* Wg; _Float16* outw; int KT, f;
    if (b < 64)       { Wg = w1;  outw = wf1;  KT = 8; f = b; }
    else if (b < 96)  { Wg = gw1; outw = wfg1; KT = 4; f = b - 64; }
    else if (b < 128) { Wg = gw2; outw = wfg2; KT = 4; f = b - 96; }
    else              { Wg = gw3; outw = wfg3; KT = 4; f = b - 128; }
    int kt = f >> 3, ct = f & 7;
    int k0 = kt * 32 + (l >> 4) * 8;
    int c = ct * 16 + (l & 15);
    f16x8 hi, lo;
    #pragma unroll
    for (int j = 0; j < 8; j++) {
        float w = Wg[(size_t)(k0 + j) * H + c];
        _Float16 hh = (_Float16)w;
        hi[j] = hh;
        lo[j] = (_Float16)(w - (float)hh);
    }
    *reinterpret_cast<f16x8*>(outw + ((size_t)f * 64 + l) * 8) = hi;
    *reinterpret_cast<f16x8*>(outw + ((size_t)KT * 8 * 64 * 8) + ((size_t)f * 64 + l) * 8) = lo;
}

// ---------------- Linear via fp16-split MFMA + LDS-staged B-frags ----------------
// ALL A-chunks loaded upfront into regs (latency paid once, not per-kt).
// B-frags double-buffered in LDS (reg-stage + ds_write_b128). AIN 0: fp32 A,
// 3-pass split. AIN 1: fp16 A, 2-pass.
// OMODE 0: fp32 out.  OMODE 1: fp16 out scaled by dis[r].  POOL: fused mean-pool.

template <int K, bool LN, int OMODE, bool POOL, int AIN>
__launch_bounds__(256)
__global__ void mfma_linear(const void* __restrict__ Ap, const _Float16* __restrict__ Wf,
                            const float* __restrict__ bias,
                            const float* __restrict__ ln_g, const float* __restrict__ ln_b,
                            const float* __restrict__ dis, const int* __restrict__ batch,
                            void* __restrict__ outp) {
    constexpr int KT = K / 32;
    __shared__ __align__(16) _Float16 stage[2][8192];   // [buf][hi 4096 | lo 4096] f16
    int t = threadIdx.x;
    int wv = t >> 6, l = t & 63;
    int lm = l & 15, lg = l >> 4;
    int rowBase = blockIdx.x * 64;
    int arow = rowBase + wv * 16 + lm;
    int arc = min(arow, NN - 1);
    const float* A32 = (const float*)Ap;
    const _Float16* A16 = (const _Float16*)Ap;
    const f16x8* __restrict__ BhG = reinterpret_cast<const f16x8*>(Wf);
    const f16x8* __restrict__ BlG = BhG + KT * 8 * 64;

    auto stage_kt = [&](int b, int kt) {
        f16x8* dstH = reinterpret_cast<f16x8*>(&stage[b][0]);
        f16x8* dstL = reinterpret_cast<f16x8*>(&stage[b][4096]);
        int wo = wv * 128 + l;
        #pragma unroll
        for (int i = 0; i < 2; i++) {
            int o = wo + i * 64;
            dstH[o] = BhG[(size_t)kt * 512 + o];
            dstL[o] = BlG[(size_t)kt * 512 + o];
        }
    };

    // ---- load ALL A-chunks upfront (independent loads; latency paid once) ----
    float4 aAll[16]; f16x8 aAll16[8];
    if constexpr (AIN == 0) {
        #pragma unroll
        for (int kt = 0; kt < KT; kt++) {
            const float* ap = A32 + (size_t)arc * K + kt * 32 + lg * 8;
            aAll[2 * kt]     = *(const float4*)ap;
            aAll[2 * kt + 1] = *(const float4*)(ap + 4);
        }
    } else {
        #pragma unroll
        for (int kt = 0; kt < KT; kt++)
            aAll16[kt] = *(const f16x8*)(A16 + (size_t)arc * K + kt * 32 + lg * 8);
    }

    f32x4 acc[8];
    #pragma unroll
    for (int ct = 0; ct < 8; ct++) acc[ct] = (f32x4){0.f, 0.f, 0.f, 0.f};

    stage_kt(0, 0);
    __syncthreads();
    int buf = 0;
    #pragma unroll
    for (int kt = 0; kt < KT; kt++) {
        if (kt + 1 < KT) stage_kt(buf ^ 1, kt + 1);   // B prefetch -> LDS
        f16x8 ah, al;
        if constexpr (AIN == 0) {
            float4 a0c = aAll[2 * kt], a1c = aAll[2 * kt + 1];
            float av[8] = {a0c.x, a0c.y, a0c.z, a0c.w, a1c.x, a1c.y, a1c.z, a1c.w};
            #pragma unroll
            for (int j = 0; j < 8; j++) {
                _Float16 hh = (_Float16)av[j];
                ah[j] = hh;
                al[j] = (_Float16)(av[j] - (float)hh);
            }
        } else {
            ah = aAll16[kt];
        }
        #pragma unroll
        for (int ct = 0; ct < 8; ct++) {
            f16x8 bh = *reinterpret_cast<const f16x8*>(&stage[buf][(ct * 64 + l) * 8]);
            f16x8 bl = *reinterpret_cast<const f16x8*>(&stage[buf][4096 + (ct * 64 + l) * 8]);
            acc[ct] = __builtin_amdgcn_mfma_f32_16x16x32_f16(ah, bh, acc[ct], 0, 0, 0);
            acc[ct] = __builtin_amdgcn_mfma_f32_16x16x32_f16(ah, bl, acc[ct], 0, 0, 0);
            if constexpr (AIN == 0)
                acc[ct] = __builtin_amdgcn_mfma_f32_16x16x32_f16(al, bh, acc[ct], 0, 0, 0);
        }
        __syncthreads();
        buf ^= 1;
    }

    float bv[8], gv[8], lbv[8];
    #pragma unroll
    for (int ct = 0; ct < 8; ct++) {
        int c = ct * 16 + lm;
        bv[ct] = bias[c];
        if constexpr (LN) { gv[ct] = ln_g[c]; lbv[ct] = ln_b[c]; }
    }

    float vals[4][8];
    #pragma unroll
    for (int q = 0; q < 4; q++) {
        float s = 0.f, sq = 0.f;
        #pragma unroll
        for (int ct = 0; ct < 8; ct++) {
            float v = fmaxf(acc[ct][q] + bv[ct], 0.f);
            vals[q][ct] = v;
            s += v; sq += v * v;
        }
        if constexpr (LN) {
            #pragma unroll
            for (int m = 1; m < 16; m <<= 1) {
                s  += __shfl_xor(s,  m, 64);
                sq += __shfl_xor(sq, m, 64);
            }
            float mean = s * (1.f / 128.f);
            float var  = sq * (1.f / 128.f) - mean * mean;
            float inv  = rsqrtf(var + 1e-5f);
            #pragma unroll
            for (int ct = 0; ct < 8; ct++)
                vals[q][ct] = (vals[q][ct] - mean) * inv * gv[ct] + lbv[ct];
        }
    }

    if constexpr (POOL) {
        __shared__ float tile[64][129];
        __shared__ int bl64[64];
        float* psums = (float*)outp;
        #pragma unroll
        for (int q = 0; q < 4; q++) {
            int r64 = wv * 16 + lg * 4 + q;
            #pragma unroll
            for (int ct = 0; ct < 8; ct++)
                tile[r64][ct * 16 + lm] = vals[q][ct];
        }
        if (t < 64) bl64[t] = batch[min(rowBase + t, NN - 1)];
        __syncthreads();
        if (t < H) {
            float pacc = 0.f;
            int curb = bl64[0];
            int rmax = min(64, NN - rowBase);
            for (int r = 0; r < rmax; r++) {
                int b = bl64[r];
                if (b != curb) {
                    atomicAdd(&psums[curb * H + t], pacc);
                    pacc = 0.f; curb = b;
                }
                pacc += tile[r][t];
            }
            atomicAdd(&psums[curb * H + t], pacc);
        }
    } else {
        #pragma unroll
        for (int q = 0; q < 4; q++) {
            int rr = rowBase + wv * 16 + lg * 4 + q;
            if (rr < NN) {
                if constexpr (OMODE == 1) {
                    _Float16* o16 = (_Float16*)outp;
                    float sc = dis[rr];
                    #pragma unroll
                    for (int ct = 0; ct < 8; ct++)
                        o16[(size_t)rr * H + ct * 16 + lm] = (_Float16)(vals[q][ct] * sc);
                } else {
                    float* o32 = (float*)outp;
                    #pragma unroll
                    for (int ct = 0; ct < 8; ct++)
                        o32[(size_t)rr * H + ct * 16 + lm] = vals[q][ct];
                }
            }
        }
    }
}

// ---------------- GCN aggregation: fp16 gather, fp32 accumulate, fp16 out ----------------

__launch_bounds__(256)
__global__ void agg_kernel(const _Float16* __restrict__ g16, const int* __restrict__ offs,
                           const int* __restrict__ degcnt, const int* __restrict__ csr,
                           const float* __restrict__ dis, _Float16* __restrict__ out16) {
    __shared__ int idx[8][64];
    int grp = threadIdx.x >> 5;        // 0..7
    int l = threadIdx.x & 31;
    int v = blockIdx.x * 8 + grp;      // grid exact: NN/8 blocks
    int beg = offs[v], cnt = degcnt[v];
    idx[grp][l]      = (l      < cnt) ? csr[beg + l]      : v;
    idx[grp][l + 32] = (l + 32 < cnt) ? csr[beg + l + 32] : v;

    const f16x4* __restrict__ G = reinterpret_cast<const f16x4*>(g16);  // 32 f16x4/row
    float dv = dis[v];
    f16x4 gvh = G[(size_t)v * 32 + l];
    float4 gv = make_float4((float)gvh[0], (float)gvh[1], (float)gvh[2], (float)gvh[3]);
    float4 acc = gv;                       // self term
    int n0 = min(cnt, 64);
    int m0 = (n0 + 7) & ~7;                // padded trip count

    for (int i = 0; i < m0; i += 8) {
        f16x4 tv[8];
        #pragma unroll
        for (int jj = 0; jj < 8; jj++)
            tv[jj] = G[(size_t)idx[grp][i + jj] * 32 + l];
        #pragma unroll
        for (int jj = 0; jj < 8; jj++) {
            acc.x += (float)tv[jj][0];
            acc.y += (float)tv[jj][1];
            acc.z += (float)tv[jj][2];
            acc.w += (float)tv[jj][3];
        }
    }
    float pad = (float)(m0 - n0);          // remove padded copies of g16[v]
    acc.x -= pad * gv.x; acc.y -= pad * gv.y;
    acc.z -= pad * gv.z; acc.w -= pad * gv.w;

    for (int i = 64; i < cnt; i++) {       // degree > 64 tail (essentially never)
        f16x4 a = G[(size_t)csr[beg + i] * 32 + l];
        acc.x += (float)a[0]; acc.y += (float)a[1];
        acc.z += (float)a[2]; acc.w += (float)a[3];
    }
    f16x4 o;
    o[0] = (_Float16)(dv * acc.x); o[1] = (_Float16)(dv * acc.y);
    o[2] = (_Float16)(dv * acc.z); o[3] = (_Float16)(dv * acc.w);
    reinterpret_cast<f16x4*>(out16)[(size_t)v * 32 + l] = o;
}

// ---------------- memory K/V projection ----------------

__global__ void kv_kernel(const float* __restrict__ mb, const float* __restrict__ ipw,
                          const float* __restrict__ ipb,
                          float* __restrict__ kbuf, float* __restrict__ vbuf) {
    __shared__ float rowv[H];
    int m = blockIdx.x, i = threadIdx.x;
    rowv[i] = mb[m * H + i];
    __syncthreads();
    float ak = 0.f, av = 0.f;
    for (int j = 0; j < H; j++) {
        float x = rowv[j];
        ak = fmaf(x, ipw[(size_t)(H + i) * H + j], ak);
        av = fmaf(x, ipw[(size_t)(2 * H + i) * H + j], av);
    }
    kbuf[m * H + i] = ak + ipb[H + i];
    vbuf[m * H + i] = av + ipb[2 * H + i];
}

// ---------------- attention + classifier (one block per graph) ----------------

__launch_bounds__(128)
__global__ void attn_kernel(const float* __restrict__ psums, const int* __restrict__ gstart,
                            const float* __restrict__ kbuf, const float* __restrict__ vbuf,
                            const float* __restrict__ ipw, const float* __restrict__ ipb,
                            const float* __restrict__ out_w, const float* __restrict__ out_b,
                            const float* __restrict__ cw1, const float* __restrict__ cb1,
                            const float* __restrict__ cw2, const float* __restrict__ cb2,
                            float* __restrict__ out) {
    __shared__ float pooled[H], q[H], attn[H], z[2 * H], c1[H], sc[NHEAD * MM];
    int b = blockIdx.x, t = threadIdx.x;
    float cn = (float)max(gstart[b + 1] - gstart[b], 1);
    float pv = psums[b * H + t] / cn;
    pooled[t] = pv;
    z[t] = pv;
    __syncthreads();
    float a = 0.f;
    for (int j = 0; j < H; j++) a = fmaf(pooled[j], ipw[(size_t)t * H + j], a);
    q[t] = a + ipb[t];
    __syncthreads();
    for (int sidx = t; sidx < NHEAD * MM; sidx += 128) {
        int hh = sidx >> 6, m = sidx & 63;
        float s2 = 0.f;
        for (int d = 0; d < HDIM; d++)
            s2 = fmaf(q[hh * HDIM + d], kbuf[m * H + hh * HDIM + d], s2);
        sc[sidx] = s2 * 0.25f;   // 1/sqrt(16)
    }
    __syncthreads();
    if (t < NHEAD) {
        float mx = -1e30f;
        for (int m = 0; m < MM; m++) mx = fmaxf(mx, sc[t * MM + m]);
        float ssum = 0.f;
        for (int m = 0; m < MM; m++) { float e = expf(sc[t * MM + m] - mx); sc[t * MM + m] = e; ssum += e; }
        float inv = 1.f / ssum;
        for (int m = 0; m < MM; m++) sc[t * MM + m] *= inv;
    }
    __syncthreads();
    {
        int hh = t >> 4;
        float a2 = 0.f;
        for (int m = 0; m < MM; m++) a2 = fmaf(sc[hh * MM + m], vbuf[m * H + t], a2);
        attn[t] = a2;
    }
    __syncthreads();
    float mm = 0.f;
    for (int j = 0; j < H; j++) mm = fmaf(attn[j], out_w[(size_t)t * H + j], mm);
    z[H + t] = mm + out_b[t];
    __syncthreads();
    float cc = 0.f;
    for (int j = 0; j < 2 * H; j++) cc = fmaf(z[j], cw1[(size_t)j * H + t], cc);
    c1[t] = fmaxf(cc + cb1[t], 0.f);
    __syncthreads();
    if (t < CC) {
        float o = 0.f;
        for (int j = 0; j < H; j++) o = fmaf(c1[j], cw2[j * CC + t], o);
        out[b * CC + t] = o + cb2[t];
    }
}

// ---------------- launch ----------------

extern "C" void kernel_launch(void* const* d_in, const int* in_sizes, int n_in,
                              void* d_out, int out_size, void* d_ws, size_t ws_size,
                              hipStream_t stream) {
    const float* x      = (const float*)d_in[0];
    const int*   eidx   = (const int*)d_in[1];
    const int*   batch  = (const int*)d_in[2];
    const float* w1     = (const float*)d_in[3];
    const float* b1     = (const float*)d_in[4];
    const float* ln_g   = (const float*)d_in[5];
    const float* ln_b   = (const float*)d_in[6];
    const float* gw1    = (const float*)d_in[7];
    const float* gb1    = (const float*)d_in[8];
    const float* gw2    = (const float*)d_in[9];
    const float* gb2    = (const float*)d_in[10];
    const float* gw3    = (const float*)d_in[11];
    const float* gb3    = (const float*)d_in[12];
    const float* memb   = (const float*)d_in[13];
    const float* ipw    = (const float*)d_in[14];
    const float* ipb    = (const float*)d_in[15];
    const float* out_w  = (const float*)d_in[16];
    const float* out_b  = (const float*)d_in[17];
    const float* cw1    = (const float*)d_in[18];
    const float* cb1    = (const float*)d_in[19];
    const float* cw2    = (const float*)d_in[20];
    const float* cb2    = (const float*)d_in[21];

    const int* row = eidx;
    const int* col = eidx + EE;

    char* ws = (char*)d_ws;
    size_t off = 0;
    auto alloc = [&](size_t bytes) -> void* {
        void* p = ws + off;
        off += (bytes + 255) & ~(size_t)255;
        return p;
    };
    _Float16* a16 = (_Float16*)alloc((size_t)NN * H * 2);   // agg output (fp16)
    _Float16* g16 = (_Float16*)alloc((size_t)NN * H * 2);   // gather array (fp16)
    char*  zbeg   = ws + off;
    float* psums  = (float*)alloc((size_t)BB * H * 4);
    size_t zbytes = (size_t)((ws + off) - zbeg);
    int*   degcnt = (int*)alloc((size_t)NN * 4);
    float* dis    = (float*)alloc((size_t)NN * 4);
    int*   offs   = (int*)alloc((size_t)NN * 4);
    int*   csr    = (int*)alloc((size_t)EE * 4);
    int2*  ebuf   = (int2*)alloc((size_t)EE * 8);
    int*   bcnt   = (int*)alloc((size_t)NRW * NSB * 4);
    int*   sbase  = (int*)alloc((size_t)NRW * NSB * 4);
    int*   rtot   = (int*)alloc(256);
    int*   rbase  = (int*)alloc(256);
    int*   gstart = (int*)alloc((size_t)(BB + 1) * 4);
    float* kbuf   = (float*)alloc((size_t)MM * H * 4);
    float* vbuf   = (float*)alloc((size_t)MM * H * 4);
    _Float16* wf1 = (_Float16*)alloc((size_t)2 * DIN * H * 2);   // 256 KB (hi+lo)
    _Float16* wfg1 = (_Float16*)alloc((size_t)2 * H * H * 2);    // 128 KB
    _Float16* wfg2 = (_Float16*)alloc((size_t)2 * H * H * 2);
    _Float16* wfg3 = (_Float16*)alloc((size_t)2 * H * H * 2);
    (void)ws_size; (void)in_sizes; (void)n_in; (void)out_size;

    hipMemsetAsync(zbeg, 0, zbytes, stream);   // psums

    // CSR build: fully-parallel two-level counting sort
    ecount<<<NSB, 256, 0, stream>>>(col, bcnt);
    erange_tot<<<NRW, 256, 0, stream>>>(bcnt, rtot);
    rscan<<<1, 64, 0, stream>>>(rtot, rbase);
    esbase<<<NRW, 256, 0, stream>>>(bcnt, rbase, sbase);
    escatter<<<NSB, 256, 0, stream>>>(row, col, sbase, ebuf);
    csr_build<<<NRW, 512, 0, stream>>>(ebuf, rbase, degcnt, offs, dis, csr);

    graph_bounds<<<(NN + 255) / 256, 256, 0, stream>>>(batch, gstart);

    // W-split precompute: one launch for all 4 weights
    wsplit_all<<<160, 64, 0, stream>>>(w1, gw1, gw2, gw3, wf1, wfg1, wfg2, wfg3);

    const int LGRID = (NN + 63) / 64;   // 782
    const int AGRID = NN / 8;           // 6250 (exact)

    // feature transform (fp32 A, 3-pass) -> g1 (fp16, dis-scaled)
    mfma_linear<DIN, true, 1, false, 0><<<LGRID, 256, 0, stream>>>(x, wf1, b1, ln_g, ln_b, dis, nullptr, g16);

    // GCN layer 1 (fp16 A, 2-pass)
    agg_kernel<<<AGRID, 256, 0, stream>>>(g16, offs, degcnt, csr, dis, a16);
    mfma_linear<H, false, 1, false, 1><<<LGRID, 256, 0, stream>>>(a16, wfg1, gb1, nullptr, nullptr, dis, nullptr, g16);
    // GCN layer 2
    agg_kernel<<<AGRID, 256, 0, stream>>>(g16, offs, degcnt, csr, dis, a16);
    mfma_linear<H, false, 1, false, 1><<<LGRID, 256, 0, stream>>>(a16, wfg2, gb2, nullptr, nullptr, dis, nullptr, g16);
    // GCN layer 3: fused mean-pool epilogue
    agg_kernel<<<AGRID, 256, 0, stream>>>(g16, offs, degcnt, csr, dis, a16);
    mfma_linear<H, false, 0, true, 1><<<LGRID, 256, 0, stream>>>(a16, wfg3, gb3, nullptr, nullptr, dis, batch, psums);

    kv_kernel<<<MM, H, 0, stream>>>(memb, ipw, ipb, kbuf, vbuf);
    attn_kernel<<<BB, H, 0, stream>>>(psums, gstart, kbuf, vbuf, ipw, ipb, out_w, out_b,
                                      cw1, cb1, cw2, cb2, (float*)d_out);
}

// Round 19
// 234.617 us; speedup vs baseline: 1.3798x; 1.0056x over previous
//
#include <hip/hip_runtime.h>

#define NN 50000
#define EE 800000
#define DIN 256
#define H 128
#define MM 64
#define CC 4
#define BB 128
#define NHEAD 8
#define HDIM 16

#define NRW 50          // node ranges (1000 nodes each)
#define RNODES 1000
#define NSB 625         // edge-slice blocks
#define ESL 1280        // edges per slice block (NSB*ESL == EE)

typedef _Float16 f16x8 __attribute__((ext_vector_type(8)));
typedef _Float16 f16x4 __attribute__((ext_vector_type(4)));
typedef float f32x4 __attribute__((ext_vector_type(4)));

// ---------------- CSR build: two-level counting sort (SoA edge buffer) ----------------

__launch_bounds__(256)
__global__ void ecount(const int* __restrict__ col, int* __restrict__ bcnt) {
    __shared__ int hist[NRW];
    int b = blockIdx.x, t = threadIdx.x;
    if (t < NRW) hist[t] = 0;
    __syncthreads();
    int e0 = b * ESL;
    #pragma unroll
    for (int i = 0; i < ESL / 256; i++) {
        int c = col[e0 + t + i * 256];
        atomicAdd(&hist[c / RNODES], 1);
    }
    __syncthreads();
    if (t < NRW) bcnt[t * NSB + b] = hist[t];
}

// per-range totals (parallel reduce; 50 blocks)
__launch_bounds__(256)
__global__ void erange_tot(const int* __restrict__ bcnt, int* __restrict__ rtot) {
    __shared__ int red[4];
    int r = blockIdx.x, t = threadIdx.x;
    int s = 0;
    for (int b = t; b < NSB; b += 256) s += bcnt[r * NSB + b];
    #pragma unroll
    for (int m = 1; m < 64; m <<= 1) s += __shfl_xor(s, m, 64);
    if ((t & 63) == 0) red[t >> 6] = s;
    __syncthreads();
    if (t == 0) rtot[r] = red[0] + red[1] + red[2] + red[3];
}

__global__ void rscan(const int* __restrict__ rtot, int* __restrict__ rbase) {
    if (threadIdx.x == 0 && blockIdx.x == 0) {
        int run = 0;
        for (int i = 0; i < NRW; i++) { rbase[i] = run; run += rtot[i]; }
    }
}

// per-range exclusive scan over slice blocks (chunked block-scan; 50 blocks)
__launch_bounds__(256)
__global__ void esbase(const int* __restrict__ bcnt, const int* __restrict__ rbase,
                       int* __restrict__ sbase) {
    __shared__ int sb[256];
    __shared__ int carry;
    int r = blockIdx.x, t = threadIdx.x;
    if (t == 0) carry = rbase[r];
    __syncthreads();
    for (int base = 0; base < NSB; base += 256) {
        int b = base + t;
        int v = (b < NSB) ? bcnt[r * NSB + b] : 0;
        sb[t] = v;
        __syncthreads();
        for (int off = 1; off < 256; off <<= 1) {
            int x = (t >= off) ? sb[t - off] : 0;
            __syncthreads();
            sb[t] += x;
            __syncthreads();
        }
        if (b < NSB) sbase[r * NSB + b] = carry + sb[t] - v;   // exclusive
        __syncthreads();
        if (t == 255) carry += sb[255];
        __syncthreads();
    }
}

__launch_bounds__(256)
__global__ void escatter(const int* __restrict__ row, const int* __restrict__ col,
                         const int* __restrict__ sbase, int* __restrict__ erow,
                         unsigned short* __restrict__ ecol) {
    __shared__ int cur[NRW];
    int b = blockIdx.x, t = threadIdx.x;
    if (t < NRW) cur[t] = sbase[t * NSB + b];
    __syncthreads();
    int e0 = b * ESL;
    #pragma unroll
    for (int i = 0; i < ESL / 256; i++) {
        int e = e0 + t + i * 256;
        int c = col[e];
        int u = row[e];
        int r = c / RNODES;
        int p = atomicAdd(&cur[r], 1);
        erow[p] = u;
        ecol[p] = (unsigned short)(c - r * RNODES);
    }
}

__launch_bounds__(1024)
__global__ void csr_build(const int* __restrict__ erow, const unsigned short* __restrict__ ecol,
                          const int* __restrict__ rbase,
                          int* __restrict__ degcnt, int* __restrict__ offs,
                          float* __restrict__ dis, int* __restrict__ csr) {
    __shared__ int hist[RNODES];
    __shared__ int cur[RNODES];
    __shared__ int sb[1024];
    int r = blockIdx.x, t = threadIdx.x;
    int r0 = r * RNODES;
    int rb = rbase[r];
    int re = (r + 1 < NRW) ? rbase[r + 1] : EE;
    if (t < RNODES) hist[t] = 0;
    __syncthreads();
    for (int e = rb + t; e < re; e += 1024) atomicAdd(&hist[ecol[e]], 1);
    __syncthreads();
    int d = (t < RNODES) ? hist[t] : 0;
    sb[t] = d;
    __syncthreads();
    for (int off = 1; off < 1024; off <<= 1) {
        int x = (t >= off) ? sb[t - off] : 0;
        __syncthreads();
        sb[t] += x;
        __syncthreads();
    }
    int excl = sb[t] - d;
    if (t < RNODES) {
        cur[t] = excl;
        degcnt[r0 + t] = d;
        offs[r0 + t] = rb + excl;
        dis[r0 + t] = rsqrtf((float)(d + 1));
    }
    __syncthreads();
    for (int e = rb + t; e < re; e += 1024) {
        int p = atomicAdd(&cur[ecol[e]], 1);
        csr[rb + p] = erow[e];
    }
}

// ---------------- graph boundaries (batch sorted) + psums zeroing ----------------

__global__ void graph_bounds(const int* __restrict__ batch, int* __restrict__ gstart,
                             float* __restrict__ psums) {
    int v = blockIdx.x * blockDim.x + threadIdx.x;
    if (v < BB * H) psums[v] = 0.f;
    if (v >= NN) return;
    int b = batch[v];
    if (v == 0) {
        for (int g = 0; g <= b; g++) gstart[g] = 0;
    } else {
        int pb = batch[v - 1];
        for (int g = pb + 1; g <= b; g++) gstart[g] = v;
    }
    if (v == NN - 1) {
        for (int g = b + 1; g <= BB; g++) gstart[g] = NN;
    }
}

// ---------------- W split to frag-ordered fp16 hi/lo (one launch, all 4 weights) -------

__global__ void wsplit_all(const float* __restrict__ w1, const float* __restrict__ gw1,
                           const float* __restrict__ gw2, const float* __restrict__ gw3,
                           _Float16* __restrict__ wf1, _Float16* __restrict__ wfg1,
                           _Float16* __restrict__ wfg2, _Float16* __restrict__ wfg3) {
    int b = blockIdx.x;
    int l = threadIdx.x;          // 0..63
    const float* Wg; _Float16* outw; int KT, f;
    if (b < 64)       { Wg = w1;  outw = wf1;  KT = 8; f = b; }
    else if (b < 96)  { Wg = gw1; outw = wfg1; KT = 4; f = b - 64; }
    else if (b < 128) { Wg = gw2; outw = wfg2; KT = 4; f = b - 96; }
    else              { Wg = gw3; outw = wfg3; KT = 4; f = b - 128; }
    int kt = f >> 3, ct = f & 7;
    int k0 = kt * 32 + (l >> 4) * 8;
    int c = ct * 16 + (l & 15);
    f16x8 hi, lo;
    #pragma unroll
    for (int j = 0; j < 8; j++) {
        float w = Wg[(size_t)(k0 + j) * H + c];
        _Float16 hh = (_Float16)w;
        hi[j] = hh;
        lo[j] = (_Float16)(w - (float)hh);
    }
    *reinterpret_cast<f16x8*>(outw + ((size_t)f * 64 + l) * 8) = hi;
    *reinterpret_cast<f16x8*>(outw + ((size_t)KT * 8 * 64 * 8) + ((size_t)f * 64 + l) * 8) = lo;
}

// ---------------- Linear via fp16-split MFMA + LDS-staged B-frags ----------------
// ALL A-chunks loaded upfront into regs. B-frags double-buffered in LDS.
// AIN 0: fp32 A, 3-pass split. AIN 1: fp16 A, 2-pass.
// OMODE 0: fp32 out.  OMODE 1: fp16 out scaled by dis[r].  POOL: fused mean-pool.

template <int K, bool LN, int OMODE, bool POOL, int AIN>
__launch_bounds__(256)
__global__ void mfma_linear(const void* __restrict__ Ap, const _Float16* __restrict__ Wf,
                            const float* __restrict__ bias,
                            const float* __restrict__ ln_g, const float* __restrict__ ln_b,
                            const float* __restrict__ dis, const int* __restrict__ batch,
                            void* __restrict__ outp) {
    constexpr int KT = K / 32;
    __shared__ __align__(16) _Float16 stage[2][8192];   // [buf][hi 4096 | lo 4096] f16
    int t = threadIdx.x;
    int wv = t >> 6, l = t & 63;
    int lm = l & 15, lg = l >> 4;
    int rowBase = blockIdx.x * 64;
    int arow = rowBase + wv * 16 + lm;
    int arc = min(arow, NN - 1);
    const float* A32 = (const float*)Ap;
    const _Float16* A16 = (const _Float16*)Ap;
    const f16x8* __restrict__ BhG = reinterpret_cast<const f16x8*>(Wf);
    const f16x8* __restrict__ BlG = BhG + KT * 8 * 64;

    auto stage_kt = [&](int b, int kt) {
        f16x8* dstH = reinterpret_cast<f16x8*>(&stage[b][0]);
        f16x8* dstL = reinterpret_cast<f16x8*>(&stage[b][4096]);
        int wo = wv * 128 + l;
        #pragma unroll
        for (int i = 0; i < 2; i++) {
            int o = wo + i * 64;
            dstH[o] = BhG[(size_t)kt * 512 + o];
            dstL[o] = BlG[(size_t)kt * 512 + o];
        }
    };

    // ---- load ALL A-chunks upfront (independent loads; latency paid once) ----
    float4 aAll[16]; f16x8 aAll16[8];
    if constexpr (AIN == 0) {
        #pragma unroll
        for (int kt = 0; kt < KT; kt++) {
            const float* ap = A32 + (size_t)arc * K + kt * 32 + lg * 8;
            aAll[2 * kt]     = *(const float4*)ap;
            aAll[2 * kt + 1] = *(const float4*)(ap + 4);
        }
    } else {
        #pragma unroll
        for (int kt = 0; kt < KT; kt++)
            aAll16[kt] = *(const f16x8*)(A16 + (size_t)arc * K + kt * 32 + lg * 8);
    }

    f32x4 acc[8];
    #pragma unroll
    for (int ct = 0; ct < 8; ct++) acc[ct] = (f32x4){0.f, 0.f, 0.f, 0.f};

    stage_kt(0, 0);
    __syncthreads();
    int buf = 0;
    #pragma unroll
    for (int kt = 0; kt < KT; kt++) {
        if (kt + 1 < KT) stage_kt(buf ^ 1, kt + 1);   // B prefetch -> LDS
        f16x8 ah, al;
        if constexpr (AIN == 0) {
            float4 a0c = aAll[2 * kt], a1c = aAll[2 * kt + 1];
            float av[8] = {a0c.x, a0c.y, a0c.z, a0c.w, a1c.x, a1c.y, a1c.z, a1c.w};
            #pragma unroll
            for (int j = 0; j < 8; j++) {
                _Float16 hh = (_Float16)av[j];
                ah[j] = hh;
                al[j] = (_Float16)(av[j] - (float)hh);
            }
        } else {
            ah = aAll16[kt];
        }
        #pragma unroll
        for (int ct = 0; ct < 8; ct++) {
            f16x8 bh = *reinterpret_cast<const f16x8*>(&stage[buf][(ct * 64 + l) * 8]);
            f16x8 bl = *reinterpret_cast<const f16x8*>(&stage[buf][4096 + (ct * 64 + l) * 8]);
            acc[ct] = __builtin_amdgcn_mfma_f32_16x16x32_f16(ah, bh, acc[ct], 0, 0, 0);
            acc[ct] = __builtin_amdgcn_mfma_f32_16x16x32_f16(ah, bl, acc[ct], 0, 0, 0);
            if constexpr (AIN == 0)
                acc[ct] = __builtin_amdgcn_mfma_f32_16x16x32_f16(al, bh, acc[ct], 0, 0, 0);
        }
        __syncthreads();
        buf ^= 1;
    }

    float bv[8], gv[8], lbv[8];
    #pragma unroll
    for (int ct = 0; ct < 8; ct++) {
        int c = ct * 16 + lm;
        bv[ct] = bias[c];
        if constexpr (LN) { gv[ct] = ln_g[c]; lbv[ct] = ln_b[c]; }
    }

    float vals[4][8];
    #pragma unroll
    for (int q = 0; q < 4; q++) {
        float s = 0.f, sq = 0.f;
        #pragma unroll
        for (int ct = 0; ct < 8; ct++) {
            float v = fmaxf(acc[ct][q] + bv[ct], 0.f);
            vals[q][ct] = v;
            s += v; sq += v * v;
        }
        if constexpr (LN) {
            #pragma unroll
            for (int m = 1; m < 16; m <<= 1) {
                s  += __shfl_xor(s,  m, 64);
                sq += __shfl_xor(sq, m, 64);
            }
            float mean = s * (1.f / 128.f);
            float var  = sq * (1.f / 128.f) - mean * mean;
            float inv  = rsqrtf(var + 1e-5f);
            #pragma unroll
            for (int ct = 0; ct < 8; ct++)
                vals[q][ct] = (vals[q][ct] - mean) * inv * gv[ct] + lbv[ct];
        }
    }

    if constexpr (POOL) {
        __shared__ float tile[64][129];
        __shared__ int bl64[64];
        float* psums = (float*)outp;
        #pragma unroll
        for (int q = 0; q < 4; q++) {
            int r64 = wv * 16 + lg * 4 + q;
            #pragma unroll
            for (int ct = 0; ct < 8; ct++)
                tile[r64][ct * 16 + lm] = vals[q][ct];
        }
        if (t < 64) bl64[t] = batch[min(rowBase + t, NN - 1)];
        __syncthreads();
        if (t < H) {
            float pacc = 0.f;
            int curb = bl64[0];
            int rmax = min(64, NN - rowBase);
            for (int r = 0; r < rmax; r++) {
                int b = bl64[r];
                if (b != curb) {
                    atomicAdd(&psums[curb * H + t], pacc);
                    pacc = 0.f; curb = b;
                }
                pacc += tile[r][t];
            }
            atomicAdd(&psums[curb * H + t], pacc);
        }
    } else {
        #pragma unroll
        for (int q = 0; q < 4; q++) {
            int rr = rowBase + wv * 16 + lg * 4 + q;
            if (rr < NN) {
                if constexpr (OMODE == 1) {
                    _Float16* o16 = (_Float16*)outp;
                    float sc = dis[rr];
                    #pragma unroll
                    for (int ct = 0; ct < 8; ct++)
                        o16[(size_t)rr * H + ct * 16 + lm] = (_Float16)(vals[q][ct] * sc);
                } else {
                    float* o32 = (float*)outp;
                    #pragma unroll
                    for (int ct = 0; ct < 8; ct++)
                        o32[(size_t)rr * H + ct * 16 + lm] = vals[q][ct];
                }
            }
        }
    }
}

// ---------------- GCN aggregation: fp16 gather, fp32 accumulate, fp16 out ----------------

__launch_bounds__(256)
__global__ void agg_kernel(const _Float16* __restrict__ g16, const int* __restrict__ offs,
                           const int* __restrict__ degcnt, const int* __restrict__ csr,
                           const float* __restrict__ dis, _Float16* __restrict__ out16) {
    __shared__ int idx[8][64];
    int grp = threadIdx.x >> 5;        // 0..7
    int l = threadIdx.x & 31;
    int v = blockIdx.x * 8 + grp;      // grid exact: NN/8 blocks
    int beg = offs[v], cnt = degcnt[v];
    idx[grp][l]      = (l      < cnt) ? csr[beg + l]      : v;
    idx[grp][l + 32] = (l + 32 < cnt) ? csr[beg + l + 32] : v;

    const f16x4* __restrict__ G = reinterpret_cast<const f16x4*>(g16);  // 32 f16x4/row
    float dv = dis[v];
    f16x4 gvh = G[(size_t)v * 32 + l];
    float4 gv = make_float4((float)gvh[0], (float)gvh[1], (float)gvh[2], (float)gvh[3]);
    float4 acc = gv;                       // self term
    int n0 = min(cnt, 64);
    int m0 = (n0 + 7) & ~7;                // padded trip count

    for (int i = 0; i < m0; i += 8) {
        f16x4 tv[8];
        #pragma unroll
        for (int jj = 0; jj < 8; jj++)
            tv[jj] = G[(size_t)idx[grp][i + jj] * 32 + l];
        #pragma unroll
        for (int jj = 0; jj < 8; jj++) {
            acc.x += (float)tv[jj][0];
            acc.y += (float)tv[jj][1];
            acc.z += (float)tv[jj][2];
            acc.w += (float)tv[jj][3];
        }
    }
    float pad = (float)(m0 - n0);          // remove padded copies of g16[v]
    acc.x -= pad * gv.x; acc.y -= pad * gv.y;
    acc.z -= pad * gv.z; acc.w -= pad * gv.w;

    for (int i = 64; i < cnt; i++) {       // degree > 64 tail (essentially never)
        f16x4 a = G[(size_t)csr[beg + i] * 32 + l];
        acc.x += (float)a[0]; acc.y += (float)a[1];
        acc.z += (float)a[2]; acc.w += (float)a[3];
    }
    f16x4 o;
    o[0] = (_Float16)(dv * acc.x); o[1] = (_Float16)(dv * acc.y);
    o[2] = (_Float16)(dv * acc.z); o[3] = (_Float16)(dv * acc.w);
    reinterpret_cast<f16x4*>(out16)[(size_t)v * 32 + l] = o;
}

// ---------------- memory K/V projection ----------------

__global__ void kv_kernel(const float* __restrict__ mb, const float* __restrict__ ipw,
                          const float* __restrict__ ipb,
                          float* __restrict__ kbuf, float* __restrict__ vbuf) {
    __shared__ float rowv[H];
    int m = blockIdx.x, i = threadIdx.x;
    rowv[i] = mb[m * H + i];
    __syncthreads();
    float ak = 0.f, av = 0.f;
    for (int j = 0; j < H; j++) {
        float x = rowv[j];
        ak = fmaf(x, ipw[(size_t)(H + i) * H + j], ak);
        av = fmaf(x, ipw[(size_t)(2 * H + i) * H + j], av);
    }
    kbuf[m * H + i] = ak + ipb[H + i];
    vbuf[m * H + i] = av + ipb[2 * H + i];
}

// ---------------- attention + classifier (one block per graph) ----------------

__launch_bounds__(128)
__global__ void attn_kernel(const float* __restrict__ psums, const int* __restrict__ gstart,
                            const float* __restrict__ kbuf, const float* __restrict__ vbuf,
                            const float* __restrict__ ipw, const float* __restrict__ ipb,
                            const float* __restrict__ out_w, const float* __restrict__ out_b,
                            const float* __restrict__ cw1, const float* __restrict__ cb1,
                            const float* __restrict__ cw2, const float* __restrict__ cb2,
                            float* __restrict__ out) {
    __shared__ float pooled[H], q[H], attn[H], z[2 * H], c1[H], sc[NHEAD * MM];
    int b = blockIdx.x, t = threadIdx.x;
    float cn = (float)max(gstart[b + 1] - gstart[b], 1);
    float pv = psums[b * H + t] / cn;
    pooled[t] = pv;
    z[t] = pv;
    __syncthreads();
    float a = 0.f;
    for (int j = 0; j < H; j++) a = fmaf(pooled[j], ipw[(size_t)t * H + j], a);
    q[t] = a + ipb[t];
    __syncthreads();
    for (int sidx = t; sidx < NHEAD * MM; sidx += 128) {
        int hh = sidx >> 6, m = sidx & 63;
        float s2 = 0.f;
        for (int d = 0; d < HDIM; d++)
            s2 = fmaf(q[hh * HDIM + d], kbuf[m * H + hh * HDIM + d], s2);
        sc[sidx] = s2 * 0.25f;   // 1/sqrt(16)
    }
    __syncthreads();
    if (t < NHEAD) {
        float mx = -1e30f;
        for (int m = 0; m < MM; m++) mx = fmaxf(mx, sc[t * MM + m]);
        float ssum = 0.f;
        for (int m = 0; m < MM; m++) { float e = expf(sc[t * MM + m] - mx); sc[t * MM + m] = e; ssum += e; }
        float inv = 1.f / ssum;
        for (int m = 0; m < MM; m++) sc[t * MM + m] *= inv;
    }
    __syncthreads();
    {
        int hh = t >> 4;
        float a2 = 0.f;
        for (int m = 0; m < MM; m++) a2 = fmaf(sc[hh * MM + m], vbuf[m * H + t], a2);
        attn[t] = a2;
    }
    __syncthreads();
    float mm = 0.f;
    for (int j = 0; j < H; j++) mm = fmaf(attn[j], out_w[(size_t)t * H + j], mm);
    z[H + t] = mm + out_b[t];
    __syncthreads();
    float cc = 0.f;
    for (int j = 0; j < 2 * H; j++) cc = fmaf(z[j], cw1[(size_t)j * H + t], cc);
    c1[t] = fmaxf(cc + cb1[t], 0.f);
    __syncthreads();
    if (t < CC) {
        float o = 0.f;
        for (int j = 0; j < H; j++) o = fmaf(c1[j], cw2[j * CC + t], o);
        out[b * CC + t] = o + cb2[t];
    }
}

// ---------------- launch ----------------

extern "C" void kernel_launch(void* const* d_in, const int* in_sizes, int n_in,
                              void* d_out, int out_size, void* d_ws, size_t ws_size,
                              hipStream_t stream) {
    const float* x      = (const float*)d_in[0];
    const int*   eidx   = (const int*)d_in[1];
    const int*   batch  = (const int*)d_in[2];
    const float* w1     = (const float*)d_in[3];
    const float* b1     = (const float*)d_in[4];
    const float* ln_g   = (const float*)d_in[5];
    const float* ln_b   = (const float*)d_in[6];
    const float* gw1    = (const float*)d_in[7];
    const float* gb1    = (const float*)d_in[8];
    const float* gw2    = (const float*)d_in[9];
    const float* gb2    = (const float*)d_in[10];
    const float* gw3    = (const float*)d_in[11];
    const float* gb3    = (const float*)d_in[12];
    const float* memb   = (const float*)d_in[13];
    const float* ipw    = (const float*)d_in[14];
    const float* ipb    = (const float*)d_in[15];
    const float* out_w  = (const float*)d_in[16];
    const float* out_b  = (const float*)d_in[17];
    const float* cw1    = (const float*)d_in[18];
    const float* cb1    = (const float*)d_in[19];
    const float* cw2    = (const float*)d_in[20];
    const float* cb2    = (const float*)d_in[21];

    const int* row = eidx;
    const int* col = eidx + EE;

    char* ws = (char*)d_ws;
    size_t off = 0;
    auto alloc = [&](size_t bytes) -> void* {
        void* p = ws + off;
        off += (bytes + 255) & ~(size_t)255;
        return p;
    };
    _Float16* a16 = (_Float16*)alloc((size_t)NN * H * 2);   // agg output (fp16)
    _Float16* g16 = (_Float16*)alloc((size_t)NN * H * 2);   // gather array (fp16)
    float* psums  = (float*)alloc((size_t)BB * H * 4);
    int*   degcnt = (int*)alloc((size_t)NN * 4);
    float* dis    = (float*)alloc((size_t)NN * 4);
    int*   offs   = (int*)alloc((size_t)NN * 4);
    int*   csr    = (int*)alloc((size_t)EE * 4);
    int*   erow   = (int*)alloc((size_t)EE * 4);
    unsigned short* ecol = (unsigned short*)alloc((size_t)EE * 2);
    int*   bcnt   = (int*)alloc((size_t)NRW * NSB * 4);
    int*   sbase  = (int*)alloc((size_t)NRW * NSB * 4);
    int*   rtot   = (int*)alloc(256);
    int*   rbase  = (int*)alloc(256);
    int*   gstart = (int*)alloc((size_t)(BB + 1) * 4);
    float* kbuf   = (float*)alloc((size_t)MM * H * 4);
    float* vbuf   = (float*)alloc((size_t)MM * H * 4);
    _Float16* wf1 = (_Float16*)alloc((size_t)2 * DIN * H * 2);   // 256 KB (hi+lo)
    _Float16* wfg1 = (_Float16*)alloc((size_t)2 * H * H * 2);    // 128 KB
    _Float16* wfg2 = (_Float16*)alloc((size_t)2 * H * H * 2);
    _Float16* wfg3 = (_Float16*)alloc((size_t)2 * H * H * 2);
    (void)ws_size; (void)in_sizes; (void)n_in; (void)out_size;

    // CSR build: fully-parallel two-level counting sort (SoA edge buffer)
    ecount<<<NSB, 256, 0, stream>>>(col, bcnt);
    erange_tot<<<NRW, 256, 0, stream>>>(bcnt, rtot);
    rscan<<<1, 64, 0, stream>>>(rtot, rbase);
    esbase<<<NRW, 256, 0, stream>>>(bcnt, rbase, sbase);
    escatter<<<NSB, 256, 0, stream>>>(row, col, sbase, erow, ecol);
    csr_build<<<NRW, 1024, 0, stream>>>(erow, ecol, rbase, degcnt, offs, dis, csr);

    graph_bounds<<<(NN + 255) / 256, 256, 0, stream>>>(batch, gstart, psums);

    // W-split precompute: one launch for all 4 weights
    wsplit_all<<<160, 64, 0, stream>>>(w1, gw1, gw2, gw3, wf1, wfg1, wfg2, wfg3);

    const int LGRID = (NN + 63) / 64;   // 782
    const int AGRID = NN / 8;           // 6250 (exact)

    // feature transform (fp32 A, 3-pass) -> g1 (fp16, dis-scaled)
    mfma_linear<DIN, true, 1, false, 0><<<LGRID, 256, 0, stream>>>(x, wf1, b1, ln_g, ln_b, dis, nullptr, g16);

    // GCN layer 1 (fp16 A, 2-pass)
    agg_kernel<<<AGRID, 256, 0, stream>>>(g16, offs, degcnt, csr, dis, a16);
    mfma_linear<H, false, 1, false, 1><<<LGRID, 256, 0, stream>>>(a16, wfg1, gb1, nullptr, nullptr, dis, nullptr, g16);
    // GCN layer 2
    agg_kernel<<<AGRID, 256, 0, stream>>>(g16, offs, degcnt, csr, dis, a16);
    mfma_linear<H, false, 1, false, 1><<<LGRID, 256, 0, stream>>>(a16, wfg2, gb2, nullptr, nullptr, dis, nullptr, g16);
    // GCN layer 3: fused mean-pool epilogue
    agg_kernel<<<AGRID, 256, 0, stream>>>(g16, offs, degcnt, csr, dis, a16);
    mfma_linear<H, false, 0, true, 1><<<LGRID, 256, 0, stream>>>(a16, wfg3, gb3, nullptr, nullptr, dis, batch, psums);

    kv_kernel<<<MM, H, 0, stream>>>(memb, ipw, ipb, kbuf, vbuf);
    attn_kernel<<<BB, H, 0, stream>>>(psums, gstart, kbuf, vbuf, ipw, ipb, out_w, out_b,
                                      cw1, cb1, cw2, cb2, (float*)d_out);
}